// Round 3
// baseline (121.454 us; speedup 1.0000x reference)
//
#include <hip/hip_runtime.h>

// FBSNN loss — single-dispatch: q-grid tabulation + local frag build + scan.
//
// Round 18: r17's three dispatches (memset(out), prep, main) collapse into
// ONE kernel (the 256 MiB harness workspace re-poison fill, ~40 us, is the
// dominant fixed cost; every extra dispatch+gap of ours is pure overhead).
//   Phase A (all 256 blocks): waves 0-3 build Y-net frags -> LDS; blocks
//     0..49 additionally build q-net frags -> LDS (waves 4-7), then all 16
//     waves tabulate one timestep of the 256-pt q-grid (cols 16*wv..+15),
//     store to workspace, threadfence (L2 writeback), agent-store MAGIC
//     sentinel. Sentinels are poison-proof and replay-proof: no init needed,
//     writers never wait (deadlock-free), stale MAGIC just re-reads
//     identical values.
//   Barrier: wave 0 spins on the 50 sentinels, threadfence (L2 inv), sync.
//   Phase B: stage qgrid ws->LDS; wave 0 runs the 50-step Catmull-Rom scan
//     publishing y rows via LDS release counter; waves 1..15 run the 51
//     Y-net+tangent evals reading frags via conflict-free ds_read_b128.
//   Reduction: per-block partial stored as one 8-byte {MAGIC,float} atomic
//     (value rides with sentinel, no fence); block 0 wave 0 spins on all
//     256 pairs, reduces, writes out directly. No memsets, no atomicAdd.
// Same math as r16/r17 (identical build/interp/eval) -> same absmax.

#define NPATH   4096
#define NSTEP   50
#define DT_F    0.02f
#define SQRT_DT 0.14142136f
#define SIGMA_F 0.5f
#define INV2PI  0.15915494309189535f
#define TWOPI_F 6.28318530717958648f

#define GRID_N   256
#define GRID_INV 8.0f
#define GRID_DY  0.125f

#define QG_FLOATS  (NSTEP * GRID_N)        // 12800
#define NFRAG      47
#define FRAG_FLOATS (NFRAG * 64 * 4)       // 12032

#define MAGIC 0x5AB1C0DEu

// fragment ids (16B per lane each)
#define FR_AIN(t)     (t)                          // 0..3
#define FR_AH(L,t,kk) (4 + (L)*8 + (t)*2 + (kk))   // 4..27
#define FR_AOUT(kk)   (28 + (kk))                  // 28..29
#define FR_BIN(t)     (30 + (t))                   // 30..33
#define FR_BHD(L,t)   (34 + (L)*4 + (t))           // 34..45
#define FR_BOUT       46

// workspace layout (float offsets)
#define WS_DONE 0                          // 64 ints (sentinels, 50 used)
#define WS_QG   64                         // 12800 floats
#define WS_PAIR (64 + QG_FLOATS)           // 12864: 256 x {MAGIC,float} u64

// LDS layout (float offsets)
#define L_QG    0                          // qgrid (phase B) / q-frags (phase A)
#define L_FR    QG_FLOATS                  // 12800: Y-frags
#define L_YB    (L_FR + FRAG_FLOATS)       // 24832  (51*16)
#define L_QB    (L_YB + 816)               // 25648  (50*16)
#define L_YY    (L_QB + 800)               // 26448  (51*16)
#define L_DY    (L_YY + 816)               // 27264  (51*16)
#define L_PART  (L_DY + 816)               // 28080  (16)
#define L_PROG  (L_PART + 16)              // 28096
#define SMEM_FLOATS (L_PROG + 4)
#define SMEM_BYTES  (SMEM_FLOATS * 4)      // 112,400 B

typedef __attribute__((ext_vector_type(8)))  short s16x8;
typedef __attribute__((ext_vector_type(4)))  float f32x4;
typedef __attribute__((ext_vector_type(4)))  float float4v;

#if __has_builtin(__builtin_amdgcn_cvt_pk_bf16_f32)
__device__ __forceinline__ unsigned pkbf(float a, float b) {
    auto r = __builtin_amdgcn_cvt_pk_bf16_f32(a, b);
    unsigned u; __builtin_memcpy(&u, &r, 4); return u;
}
#else
__device__ __forceinline__ unsigned pkbf(float a, float b) {
    unsigned ua = __float_as_uint(a), ub = __float_as_uint(b);
    ua += 0x7fffu + ((ua >> 16) & 1u);
    ub += 0x7fffu + ((ub >> 16) & 1u);
    return (ua >> 16) | (ub & 0xffff0000u);
}
#endif

__device__ __forceinline__ s16x8 frag4(unsigned a, unsigned b, unsigned c, unsigned d) {
    union { unsigned u[4]; s16x8 s; } x;
    x.u[0] = a; x.u[1] = b; x.u[2] = c; x.u[3] = d;
    return x.s;
}

__device__ __forceinline__ float sinrev(float x) {
#if __has_builtin(__builtin_amdgcn_sinf)
    return __builtin_amdgcn_sinf(x);
#else
    return __sinf(x * TWOPI_F);
#endif
}
__device__ __forceinline__ float cosrev(float x) {
#if __has_builtin(__builtin_amdgcn_cosf)
    return __builtin_amdgcn_cosf(x);
#else
    return __cosf(x * TWOPI_F);
#endif
}

__device__ __forceinline__ int slot16(int t, int r) {
    return (t < 2) ? 8 * (r >> 2) + 4 * t + (r & 3)
                   : 32 + 8 * (r >> 2) + 4 * (t - 2) + (r & 3);
}

// Build one section of a net's fragments straight into LDS (live set ~10
// VGPRs; no NetFrags residency). sec 0: Ain+bIn+Aout+bout; sec 1..3: layer.
__device__ __forceinline__ void build_sec(
    int sec, const float* __restrict__ Win, const float* __restrict__ bin,
    const float* __restrict__ Whid, const float* __restrict__ bhid,
    const float* __restrict__ Wout, const float* __restrict__ bo,
    int qd, int m, char* fbl)
{
    if (sec == 0) {
#pragma unroll
        for (int t = 0; t < 4; ++t) {
            const int uo = slot16(t, m);
            unsigned w0 = 0;
            if (qd == 0) w0 = pkbf(INV2PI * Win[uo], INV2PI * Win[64 + uo]);
            *reinterpret_cast<s16x8*>(fbl + FR_AIN(t) * 1024) = frag4(w0, 0u, 0u, 0u);
            f32x4 bi;
#pragma unroll
            for (int i = 0; i < 4; ++i) bi[i] = INV2PI * bin[slot16(t, 4 * qd + i)];
            *reinterpret_cast<f32x4*>(fbl + FR_BIN(t) * 1024) = bi;
        }
#pragma unroll
        for (int kk = 0; kk < 2; ++kk) {
            unsigned w[4] = {0u, 0u, 0u, 0u};
            if (m == 0) {
#pragma unroll
                for (int j2 = 0; j2 < 4; ++j2) {
                    int e0 = 32 * kk + 8 * qd + 2 * j2;
                    w[j2] = pkbf(Wout[e0], Wout[e0 + 1]);
                }
            }
            *reinterpret_cast<s16x8*>(fbl + FR_AOUT(kk) * 1024) = frag4(w[0], w[1], w[2], w[3]);
        }
        f32x4 bo4 = {bo[0], 0.0f, 0.0f, 0.0f};
        *reinterpret_cast<f32x4*>(fbl + FR_BOUT * 1024) = bo4;
    } else {
        const int L = sec - 1;
#pragma unroll
        for (int t = 0; t < 4; ++t) {
            const int uo = slot16(t, m);
            const float* W = Whid + L * 4096 + uo;
#pragma unroll
            for (int kk = 0; kk < 2; ++kk) {
                unsigned w[4];
#pragma unroll
                for (int j2 = 0; j2 < 4; ++j2) {
                    int e0 = 32 * kk + 8 * qd + 2 * j2;
                    w[j2] = pkbf(INV2PI * W[e0 * 64], INV2PI * W[(e0 + 1) * 64]);
                }
                *reinterpret_cast<s16x8*>(fbl + FR_AH(L, t, kk) * 1024) = frag4(w[0], w[1], w[2], w[3]);
            }
            f32x4 bh;
#pragma unroll
            for (int i = 0; i < 4; ++i) bh[i] = INV2PI * bhid[L * 64 + slot16(t, 4 * qd + i)];
            *reinterpret_cast<f32x4*>(fbl + FR_BHD(L, t) * 1024) = bh;
        }
    }
}

__device__ __forceinline__ void trans16(const f32x4* C, s16x8& B0, s16x8& B1) {
    float a[4][4];
#pragma unroll
    for (int t = 0; t < 4; ++t)
#pragma unroll
        for (int i = 0; i < 4; ++i) a[t][i] = sinrev(C[t][i]);
    B0 = frag4(pkbf(a[0][0], a[0][1]), pkbf(a[0][2], a[0][3]),
               pkbf(a[1][0], a[1][1]), pkbf(a[1][2], a[1][3]));
    B1 = frag4(pkbf(a[2][0], a[2][1]), pkbf(a[2][2], a[2][3]),
               pkbf(a[3][0], a[3][1]), pkbf(a[3][2], a[3][3]));
}

__device__ __forceinline__ void trans16t(const f32x4* Cf, const f32x4* Ct,
                                         s16x8& Bf0, s16x8& Bf1,
                                         s16x8& Bt0, s16x8& Bt1)
{
    float s[4][4], d[4][4];
#pragma unroll
    for (int t = 0; t < 4; ++t)
#pragma unroll
        for (int i = 0; i < 4; ++i) {
            float cf = Cf[t][i];
            s[t][i] = sinrev(cf);
            d[t][i] = cosrev(cf) * (TWOPI_F * Ct[t][i]);
        }
    Bf0 = frag4(pkbf(s[0][0], s[0][1]), pkbf(s[0][2], s[0][3]),
                pkbf(s[1][0], s[1][1]), pkbf(s[1][2], s[1][3]));
    Bf1 = frag4(pkbf(s[2][0], s[2][1]), pkbf(s[2][2], s[2][3]),
                pkbf(s[3][0], s[3][1]), pkbf(s[3][2], s[3][3]));
    Bt0 = frag4(pkbf(d[0][0], d[0][1]), pkbf(d[0][2], d[0][3]),
                pkbf(d[1][0], d[1][1]), pkbf(d[1][2], d[1][3]));
    Bt1 = frag4(pkbf(d[2][0], d[2][1]), pkbf(d[2][2], d[2][3]),
                pkbf(d[3][0], d[3][1]), pkbf(d[3][2], d[3][3]));
}

__device__ __forceinline__ float grid_ylo(const float* __restrict__ y0p) {
    return floorf(y0p[0] * 8.0f) * 0.125f - 16.0f;
}

// forward-only eval (q-grid tabulation), frags from LDS at fbl = base + l*16
__device__ __forceinline__ float eval16_q(const char* fbl, const s16x8& Bty) {
    const f32x4 zc = {0.0f, 0.0f, 0.0f, 0.0f};
    f32x4 C[4];
#pragma unroll
    for (int t = 0; t < 4; ++t) {
        const s16x8 a  = *reinterpret_cast<const s16x8*>(fbl + FR_AIN(t) * 1024);
        const f32x4 bi = *reinterpret_cast<const f32x4*>(fbl + FR_BIN(t) * 1024);
        C[t] = __builtin_amdgcn_mfma_f32_16x16x32_bf16(a, Bty, bi, 0, 0, 0);
    }
    s16x8 B0, B1;
    trans16(C, B0, B1);
#pragma unroll
    for (int L = 0; L < 3; ++L) {
#pragma unroll
        for (int t = 0; t < 4; ++t) {
            const s16x8 a0 = *reinterpret_cast<const s16x8*>(fbl + FR_AH(L, t, 0) * 1024);
            const s16x8 a1 = *reinterpret_cast<const s16x8*>(fbl + FR_AH(L, t, 1) * 1024);
            const f32x4 bh = *reinterpret_cast<const f32x4*>(fbl + FR_BHD(L, t) * 1024);
            f32x4 c = __builtin_amdgcn_mfma_f32_16x16x32_bf16(a0, B0, bh, 0, 0, 0);
            C[t]    = __builtin_amdgcn_mfma_f32_16x16x32_bf16(a1, B1, c, 0, 0, 0);
        }
        trans16(C, B0, B1);
    }
    const s16x8 o0 = *reinterpret_cast<const s16x8*>(fbl + FR_AOUT(0) * 1024);
    const s16x8 o1 = *reinterpret_cast<const s16x8*>(fbl + FR_AOUT(1) * 1024);
    f32x4 Co = __builtin_amdgcn_mfma_f32_16x16x32_bf16(o0, B0, zc, 0, 0, 0);
    Co = __builtin_amdgcn_mfma_f32_16x16x32_bf16(o1, B1, Co, 0, 0, 0);
    return Co[0] + *reinterpret_cast<const float*>(fbl + FR_BOUT * 1024);
}

// ====================== the single fused kernel ======================

extern "C" __global__ void __launch_bounds__(1024, 4)
fbsnn_one(const float* __restrict__ Y_Win, const float* __restrict__ Y_bin,
          const float* __restrict__ Y_Whid, const float* __restrict__ Y_bhid,
          const float* __restrict__ Y_Wout, const float* __restrict__ Y_bout,
          const float* __restrict__ q_Win, const float* __restrict__ q_bin,
          const float* __restrict__ q_Whid, const float* __restrict__ q_bhid,
          const float* __restrict__ q_Wout, const float* __restrict__ q_bout,
          const float* __restrict__ y0p, const float* __restrict__ dW,
          float* __restrict__ ws, float* __restrict__ out)
{
    extern __shared__ __align__(16) float sf[];
    float* qg   = sf + L_QG;
    float* yb   = sf + L_YB;
    float* qb   = sf + L_QB;
    float* Yb   = sf + L_YY;
    float* dYb  = sf + L_DY;
    float* part = sf + L_PART;
    int*   prog = (int*)(sf + L_PROG);

    int* done = (int*)ws;
    float* qgw = ws + WS_QG;
    unsigned long long* pairs = (unsigned long long*)(ws + WS_PAIR);

    const int tid = (int)threadIdx.x;
    const int wv  = tid >> 6;          // 0..15; wave 0 = scanner
    const int l   = tid & 63;
    const int qd  = l >> 4;
    const int m   = l & 15;
    const int blk = (int)blockIdx.x;
    const int p   = blk * 16 + m;

    if (tid == 0) *prog = 0;
    const float dw0 = (wv == 0) ? dW[p] : 0.0f;   // early-issue scan prefetch
    const float ylo = grid_ylo(y0p);
    const f32x4 zc  = {0.0f, 0.0f, 0.0f, 0.0f};

    // ---- phase A: local frag builds ----
    if (wv < 4) {
        char* fbl = (char*)(sf + L_FR) + l * 16;
        build_sec(wv, Y_Win, Y_bin, Y_Whid, Y_bhid, Y_Wout, Y_bout, qd, m, fbl);
    } else if (wv < 8 && blk < 50) {
        char* fql = (char*)sf + l * 16;            // q-frags reuse qgrid LDS
        build_sec(wv - 4, q_Win, q_bin, q_Whid, q_bhid, q_Wout, q_bout, qd, m, fql);
    }
    __syncthreads();

    // ---- phase A: q-grid tabulation (blocks 0..49; timestep n = blk) ----
    if (blk < 50) {
        const char* fql = (const char*)sf + l * 16;
        const float tt = blk * DT_F;
        const float yg = ylo + (float)(16 * wv + m) * GRID_DY;  // k/8: exact bf16
        const s16x8 Bty = frag4((qd == 0) ? pkbf(tt, yg) : 0u, 0u, 0u, 0u);
        const float qv = eval16_q(fql, Bty);
        if (qd == 0) qgw[blk * GRID_N + 16 * wv + m] = qv;
        __syncthreads();
        if (tid == 0) {
            __threadfence();   // release: L2 writeback of qgrid row
            __hip_atomic_store(&done[blk], (int)MAGIC, __ATOMIC_RELAXED,
                               __HIP_MEMORY_SCOPE_AGENT);
        }
    }

    // ---- device barrier: wait for all 50 grid rows (deadlock-free) ----
    if (wv == 0) {
        if (l < 50)
            while (__hip_atomic_load(&done[l], __ATOMIC_RELAXED,
                                     __HIP_MEMORY_SCOPE_AGENT) != (int)MAGIC)
                __builtin_amdgcn_s_sleep(8);
        __threadfence();       // acquire: L2 invalidate before staging reads
    }
    __syncthreads();

    // ---- stage 0: qgrid ws -> LDS (3200 x 16B, coalesced) ----
#pragma unroll
    for (int k = 0; k < 4; ++k) {
        const int idx = tid + k * 1024;
        if (idx < 3200)
            ((float4v*)qg)[idx] = ((const float4v*)qgw)[idx];
    }
    __syncthreads();

    // ---- phase B ----
    if (wv == 0) {
        // scan: Catmull-Rom interp on the q-grid, publish rows
        float y = y0p[0];
        float dw_cur = dw0;
        for (int n = 0; n < NSTEP; ++n) {
            if (l < 16) yb[n * 16 + m] = y;
            __threadfence_block();
            if (l == 0) __hip_atomic_store(prog, n + 1, __ATOMIC_RELEASE,
                                           __HIP_MEMORY_SCOPE_WORKGROUP);
            const int n1 = (n + 1 < NSTEP) ? n + 1 : NSTEP - 1;
            const float dw_next = dW[n1 * NPATH + p];

            float u = (y - ylo) * GRID_INV;
            u = fminf(fmaxf(u, 1.0f), 253.999f);
            int i = (int)u;
            if (i > 253) i = 253;
            const float fr = u - (float)i;
            const float* row = qg + n * GRID_N + i;
            const float q0 = row[-1], q1 = row[0], q2 = row[1], q3 = row[2];
            const float qt = q1 + 0.5f * fr * ((q2 - q0)
                           + fr * ((2.0f * q0 - 5.0f * q1 + 4.0f * q2 - q3)
                           + fr * (3.0f * (q1 - q2) + q3 - q0)));

            if (l < 16) qb[n * 16 + m] = qt;
            y = fmaf(qt, DT_F, y) + SIGMA_F * (dw_cur * SQRT_DT);
            dw_cur = dw_next;
        }
        if (l < 16) yb[NSTEP * 16 + m] = y;
        __threadfence_block();
        if (l == 0) __hip_atomic_store(prog, NSTEP + 1, __ATOMIC_RELEASE,
                                       __HIP_MEMORY_SCOPE_WORKGROUP);
    } else {
        // consumers: rows (wv-1)+15j, j=0..2; waves 1..6 add 44+wv
        const char* fbl = (const char*)(sf + L_FR) + l * 16;
        const s16x8 Btn = frag4((qd == 0) ? pkbf(0.0f, 1.0f) : 0u, 0u, 0u, 0u);
        const float boutY = *reinterpret_cast<const float*>(fbl + FR_BOUT * 1024);

        const int cnt = (wv <= 6) ? 4 : 3;
        for (int j = 0; j < cnt; ++j) {
            const int k = (j < 3) ? (wv - 1) + 15 * j : 44 + wv;

            while (__hip_atomic_load(prog, __ATOMIC_ACQUIRE,
                                     __HIP_MEMORY_SCOPE_WORKGROUP) <= k)
                __builtin_amdgcn_s_sleep(2);

            const float yv = yb[k * 16 + m];
            const float tt = k * DT_F;
            const s16x8 Bty = frag4((qd == 0) ? pkbf(tt, yv) : 0u, 0u, 0u, 0u);

            f32x4 Cf[4], Ct[4];
#pragma unroll
            for (int t = 0; t < 4; ++t) {
                const s16x8 a  = *reinterpret_cast<const s16x8*>(fbl + FR_AIN(t) * 1024);
                const f32x4 bi = *reinterpret_cast<const f32x4*>(fbl + FR_BIN(t) * 1024);
                Cf[t] = __builtin_amdgcn_mfma_f32_16x16x32_bf16(a, Bty, bi, 0, 0, 0);
                Ct[t] = __builtin_amdgcn_mfma_f32_16x16x32_bf16(a, Btn, zc, 0, 0, 0);
            }
            s16x8 bf0, bf1, bt0, bt1;
            trans16t(Cf, Ct, bf0, bf1, bt0, bt1);

#pragma unroll
            for (int L = 0; L < 3; ++L) {
#pragma unroll
                for (int t = 0; t < 4; ++t) {
                    const s16x8 a0 = *reinterpret_cast<const s16x8*>(fbl + FR_AH(L, t, 0) * 1024);
                    const s16x8 a1 = *reinterpret_cast<const s16x8*>(fbl + FR_AH(L, t, 1) * 1024);
                    const f32x4 bh = *reinterpret_cast<const f32x4*>(fbl + FR_BHD(L, t) * 1024);
                    f32x4 c = __builtin_amdgcn_mfma_f32_16x16x32_bf16(a0, bf0, bh, 0, 0, 0);
                    Cf[t]   = __builtin_amdgcn_mfma_f32_16x16x32_bf16(a1, bf1, c, 0, 0, 0);
                    f32x4 z = __builtin_amdgcn_mfma_f32_16x16x32_bf16(a0, bt0, zc, 0, 0, 0);
                    Ct[t]   = __builtin_amdgcn_mfma_f32_16x16x32_bf16(a1, bt1, z, 0, 0, 0);
                }
                trans16t(Cf, Ct, bf0, bf1, bt0, bt1);
            }

            const s16x8 o0 = *reinterpret_cast<const s16x8*>(fbl + FR_AOUT(0) * 1024);
            const s16x8 o1 = *reinterpret_cast<const s16x8*>(fbl + FR_AOUT(1) * 1024);
            f32x4 Cof = __builtin_amdgcn_mfma_f32_16x16x32_bf16(o0, bf0, zc, 0, 0, 0);
            Cof = __builtin_amdgcn_mfma_f32_16x16x32_bf16(o1, bf1, Cof, 0, 0, 0);
            f32x4 Cot = __builtin_amdgcn_mfma_f32_16x16x32_bf16(o0, bt0, zc, 0, 0, 0);
            Cot = __builtin_amdgcn_mfma_f32_16x16x32_bf16(o1, bt1, Cot, 0, 0, 0);

            if (qd == 0) {
                Yb[k * 16 + m]  = Cof[0] + boutY;
                dYb[k * 16 + m] = Cot[0];
            }
        }
    }

    // ---- epilogue: residuals + per-block reduction ----
    __syncthreads();

    float acc = 0.0f;
    if (tid < 816) {
        const int it = tid;
        if (it < 800) {
            const int n  = it >> 4;
            const int pp = it & 15;
            const float q    = qb[it];
            const float dYc  = dYb[it];
            const float Yn   = Yb[it];
            const float Yn1  = Yb[it + 16];
            const float dws  = dW[n * NPATH + blk * 16 + pp] * SQRT_DT;
            const float Ytil = fmaf(-q * q, DT_F, Yn) + (SIGMA_F * dYc) * dws;
            const float r    = Yn1 - Ytil;
            acc = fmaf(r, r, acc);
        } else {
            const int pp = it - 800;
            const float y50  = yb[NSTEP * 16 + pp];
            const float Y50  = Yb[NSTEP * 16 + pp];
            const float dY50 = dYb[NSTEP * 16 + pp];
            const float r1 = Y50 - y50 * y50;
            const float r2 = dY50 - 2.0f * y50;
            acc = fmaf(r1, r1, fmaf(r2, r2, acc));
        }
    }
#pragma unroll
    for (int off = 32; off > 0; off >>= 1) acc += __shfl_down(acc, off, 64);
    if (l == 0) part[wv] = acc;
    __syncthreads();

    // ---- cross-block reduction via {MAGIC,float} sentinel pairs ----
    if (wv == 0) {
        if (l == 0) {
            float bsum = 0.0f;
#pragma unroll
            for (int w = 0; w < 16; ++w) bsum += part[w];
            const unsigned long long pv =
                ((unsigned long long)MAGIC << 32) |
                (unsigned long long)__float_as_uint(bsum);
            __hip_atomic_store(&pairs[blk], pv, __ATOMIC_RELAXED,
                               __HIP_MEMORY_SCOPE_AGENT);
        }
        if (blk == 0) {
            float s = 0.0f;
#pragma unroll
            for (int r = 0; r < 4; ++r) {
                unsigned long long v;
                while ((unsigned)((v = __hip_atomic_load(&pairs[4 * l + r],
                                __ATOMIC_RELAXED, __HIP_MEMORY_SCOPE_AGENT)) >> 32)
                       != MAGIC)
                    __builtin_amdgcn_s_sleep(4);
                s += __uint_as_float((unsigned)(v & 0xffffffffu));
            }
#pragma unroll
            for (int off = 32; off > 0; off >>= 1) s += __shfl_down(s, off, 64);
            if (l == 0) out[0] = s * (1.0f / (float)NPATH);
        }
    }
}

// ================= host launch =================

extern "C" void kernel_launch(void* const* d_in, const int* in_sizes, int n_in,
                              void* d_out, int out_size, void* d_ws, size_t ws_size,
                              hipStream_t stream)
{
    const float* Y_Win  = (const float*)d_in[0];
    const float* Y_bin  = (const float*)d_in[1];
    const float* Y_Whid = (const float*)d_in[2];
    const float* Y_bhid = (const float*)d_in[3];
    const float* Y_Wout = (const float*)d_in[4];
    const float* Y_bout = (const float*)d_in[5];
    const float* q_Win  = (const float*)d_in[6];
    const float* q_bin  = (const float*)d_in[7];
    const float* q_Whid = (const float*)d_in[8];
    const float* q_bhid = (const float*)d_in[9];
    const float* q_Wout = (const float*)d_in[10];
    const float* q_bout = (const float*)d_in[11];
    const float* y0p    = (const float*)d_in[12];
    const float* dW     = (const float*)d_in[13];

    fbsnn_one<<<dim3(NPATH / 16), dim3(1024), SMEM_BYTES, stream>>>(
        Y_Win, Y_bin, Y_Whid, Y_bhid, Y_Wout, Y_bout,
        q_Win, q_bin, q_Whid, q_bhid, q_Wout, q_bout,
        y0p, dW, (float*)d_ws, (float*)d_out);
}

// Round 4
// 119.733 us; speedup vs baseline: 1.0144x; 1.0144x over previous
//
#include <hip/hip_runtime.h>

// FBSNN loss — single-dispatch: q-grid tabulation + local frag build + scan.
//
// Round 19 = round 18 with the scan-loop fence stall removed:
//   * dW for the block (50x16 floats) is staged into LDS during phase A by
//     the otherwise-idle waves 8-15. The scan loop and the epilogue read dW
//     from LDS -> the scan loop has ZERO global memory ops.
//   * The per-step __threadfence_block() (which emits a vmcnt(0)+lgkmcnt(0)
//     drain and was serializing the dW prefetch at ~700 cyc/step) is gone;
//     the RELEASE atomic store on the LDS prog counter orders the same-wave
//     yb writes by itself (lgkmcnt only).
// Structure otherwise identical to r18:
//   Phase A (all 256 blocks): waves 0-3 build Y-net frags -> LDS; blocks
//     0..49 also build q-net frags (waves 4-7); waves 8-15 stage dW -> LDS;
//     blocks 0..49 then tabulate one timestep of the 256-pt q-grid, store to
//     workspace, threadfence (L2 writeback), agent-store MAGIC sentinel
//     (poison-proof, replay-proof, writers never wait).
//   Barrier: wave 0 spins on the 50 sentinels, threadfence, sync.
//   Phase B: stage qgrid ws->LDS; wave 0 runs the 50-step Catmull-Rom scan
//     (LDS-only) publishing y rows via release counter; waves 1..15 run the
//     51 Y-net+tangent evals reading frags via conflict-free ds_read_b128.
//   Reduction: per-block partial as one 8-byte {MAGIC,float} pair; block 0
//     wave 0 spins on all 256 pairs, reduces, writes out directly.
// Same math as r16-r18 (identical build/interp/eval) -> same absmax.

#define NPATH   4096
#define NSTEP   50
#define DT_F    0.02f
#define SQRT_DT 0.14142136f
#define SIGMA_F 0.5f
#define INV2PI  0.15915494309189535f
#define TWOPI_F 6.28318530717958648f

#define GRID_N   256
#define GRID_INV 8.0f
#define GRID_DY  0.125f

#define QG_FLOATS  (NSTEP * GRID_N)        // 12800
#define NFRAG      47
#define FRAG_FLOATS (NFRAG * 64 * 4)       // 12032

#define MAGIC 0x5AB1C0DEu

// fragment ids (16B per lane each)
#define FR_AIN(t)     (t)                          // 0..3
#define FR_AH(L,t,kk) (4 + (L)*8 + (t)*2 + (kk))   // 4..27
#define FR_AOUT(kk)   (28 + (kk))                  // 28..29
#define FR_BIN(t)     (30 + (t))                   // 30..33
#define FR_BHD(L,t)   (34 + (L)*4 + (t))           // 34..45
#define FR_BOUT       46

// workspace layout (float offsets)
#define WS_DONE 0                          // 64 ints (sentinels, 50 used)
#define WS_QG   64                         // 12800 floats
#define WS_PAIR (64 + QG_FLOATS)           // 12864: 256 x {MAGIC,float} u64

// LDS layout (float offsets)
#define L_QG    0                          // qgrid (phase B) / q-frags (phase A)
#define L_FR    QG_FLOATS                  // 12800: Y-frags
#define L_YB    (L_FR + FRAG_FLOATS)       // 24832  (51*16)
#define L_QB    (L_YB + 816)               // 25648  (50*16)
#define L_YY    (L_QB + 800)               // 26448  (51*16)
#define L_DY    (L_YY + 816)               // 27264  (51*16)
#define L_DW    (L_DY + 816)               // 28080  (50*16)
#define L_PART  (L_DW + 800)               // 28880  (16)
#define L_PROG  (L_PART + 16)              // 28896
#define SMEM_FLOATS (L_PROG + 4)
#define SMEM_BYTES  (SMEM_FLOATS * 4)      // 115,600 B

typedef __attribute__((ext_vector_type(8)))  short s16x8;
typedef __attribute__((ext_vector_type(4)))  float f32x4;
typedef __attribute__((ext_vector_type(4)))  float float4v;

#if __has_builtin(__builtin_amdgcn_cvt_pk_bf16_f32)
__device__ __forceinline__ unsigned pkbf(float a, float b) {
    auto r = __builtin_amdgcn_cvt_pk_bf16_f32(a, b);
    unsigned u; __builtin_memcpy(&u, &r, 4); return u;
}
#else
__device__ __forceinline__ unsigned pkbf(float a, float b) {
    unsigned ua = __float_as_uint(a), ub = __float_as_uint(b);
    ua += 0x7fffu + ((ua >> 16) & 1u);
    ub += 0x7fffu + ((ub >> 16) & 1u);
    return (ua >> 16) | (ub & 0xffff0000u);
}
#endif

__device__ __forceinline__ s16x8 frag4(unsigned a, unsigned b, unsigned c, unsigned d) {
    union { unsigned u[4]; s16x8 s; } x;
    x.u[0] = a; x.u[1] = b; x.u[2] = c; x.u[3] = d;
    return x.s;
}

__device__ __forceinline__ float sinrev(float x) {
#if __has_builtin(__builtin_amdgcn_sinf)
    return __builtin_amdgcn_sinf(x);
#else
    return __sinf(x * TWOPI_F);
#endif
}
__device__ __forceinline__ float cosrev(float x) {
#if __has_builtin(__builtin_amdgcn_cosf)
    return __builtin_amdgcn_cosf(x);
#else
    return __cosf(x * TWOPI_F);
#endif
}

__device__ __forceinline__ int slot16(int t, int r) {
    return (t < 2) ? 8 * (r >> 2) + 4 * t + (r & 3)
                   : 32 + 8 * (r >> 2) + 4 * (t - 2) + (r & 3);
}

// Build one section of a net's fragments straight into LDS (live set ~10
// VGPRs; no NetFrags residency). sec 0: Ain+bIn+Aout+bout; sec 1..3: layer.
__device__ __forceinline__ void build_sec(
    int sec, const float* __restrict__ Win, const float* __restrict__ bin,
    const float* __restrict__ Whid, const float* __restrict__ bhid,
    const float* __restrict__ Wout, const float* __restrict__ bo,
    int qd, int m, char* fbl)
{
    if (sec == 0) {
#pragma unroll
        for (int t = 0; t < 4; ++t) {
            const int uo = slot16(t, m);
            unsigned w0 = 0;
            if (qd == 0) w0 = pkbf(INV2PI * Win[uo], INV2PI * Win[64 + uo]);
            *reinterpret_cast<s16x8*>(fbl + FR_AIN(t) * 1024) = frag4(w0, 0u, 0u, 0u);
            f32x4 bi;
#pragma unroll
            for (int i = 0; i < 4; ++i) bi[i] = INV2PI * bin[slot16(t, 4 * qd + i)];
            *reinterpret_cast<f32x4*>(fbl + FR_BIN(t) * 1024) = bi;
        }
#pragma unroll
        for (int kk = 0; kk < 2; ++kk) {
            unsigned w[4] = {0u, 0u, 0u, 0u};
            if (m == 0) {
#pragma unroll
                for (int j2 = 0; j2 < 4; ++j2) {
                    int e0 = 32 * kk + 8 * qd + 2 * j2;
                    w[j2] = pkbf(Wout[e0], Wout[e0 + 1]);
                }
            }
            *reinterpret_cast<s16x8*>(fbl + FR_AOUT(kk) * 1024) = frag4(w[0], w[1], w[2], w[3]);
        }
        f32x4 bo4 = {bo[0], 0.0f, 0.0f, 0.0f};
        *reinterpret_cast<f32x4*>(fbl + FR_BOUT * 1024) = bo4;
    } else {
        const int L = sec - 1;
#pragma unroll
        for (int t = 0; t < 4; ++t) {
            const int uo = slot16(t, m);
            const float* W = Whid + L * 4096 + uo;
#pragma unroll
            for (int kk = 0; kk < 2; ++kk) {
                unsigned w[4];
#pragma unroll
                for (int j2 = 0; j2 < 4; ++j2) {
                    int e0 = 32 * kk + 8 * qd + 2 * j2;
                    w[j2] = pkbf(INV2PI * W[e0 * 64], INV2PI * W[(e0 + 1) * 64]);
                }
                *reinterpret_cast<s16x8*>(fbl + FR_AH(L, t, kk) * 1024) = frag4(w[0], w[1], w[2], w[3]);
            }
            f32x4 bh;
#pragma unroll
            for (int i = 0; i < 4; ++i) bh[i] = INV2PI * bhid[L * 64 + slot16(t, 4 * qd + i)];
            *reinterpret_cast<f32x4*>(fbl + FR_BHD(L, t) * 1024) = bh;
        }
    }
}

__device__ __forceinline__ void trans16(const f32x4* C, s16x8& B0, s16x8& B1) {
    float a[4][4];
#pragma unroll
    for (int t = 0; t < 4; ++t)
#pragma unroll
        for (int i = 0; i < 4; ++i) a[t][i] = sinrev(C[t][i]);
    B0 = frag4(pkbf(a[0][0], a[0][1]), pkbf(a[0][2], a[0][3]),
               pkbf(a[1][0], a[1][1]), pkbf(a[1][2], a[1][3]));
    B1 = frag4(pkbf(a[2][0], a[2][1]), pkbf(a[2][2], a[2][3]),
               pkbf(a[3][0], a[3][1]), pkbf(a[3][2], a[3][3]));
}

__device__ __forceinline__ void trans16t(const f32x4* Cf, const f32x4* Ct,
                                         s16x8& Bf0, s16x8& Bf1,
                                         s16x8& Bt0, s16x8& Bt1)
{
    float s[4][4], d[4][4];
#pragma unroll
    for (int t = 0; t < 4; ++t)
#pragma unroll
        for (int i = 0; i < 4; ++i) {
            float cf = Cf[t][i];
            s[t][i] = sinrev(cf);
            d[t][i] = cosrev(cf) * (TWOPI_F * Ct[t][i]);
        }
    Bf0 = frag4(pkbf(s[0][0], s[0][1]), pkbf(s[0][2], s[0][3]),
                pkbf(s[1][0], s[1][1]), pkbf(s[1][2], s[1][3]));
    Bf1 = frag4(pkbf(s[2][0], s[2][1]), pkbf(s[2][2], s[2][3]),
                pkbf(s[3][0], s[3][1]), pkbf(s[3][2], s[3][3]));
    Bt0 = frag4(pkbf(d[0][0], d[0][1]), pkbf(d[0][2], d[0][3]),
                pkbf(d[1][0], d[1][1]), pkbf(d[1][2], d[1][3]));
    Bt1 = frag4(pkbf(d[2][0], d[2][1]), pkbf(d[2][2], d[2][3]),
                pkbf(d[3][0], d[3][1]), pkbf(d[3][2], d[3][3]));
}

__device__ __forceinline__ float grid_ylo(const float* __restrict__ y0p) {
    return floorf(y0p[0] * 8.0f) * 0.125f - 16.0f;
}

// forward-only eval (q-grid tabulation), frags from LDS at fbl = base + l*16
__device__ __forceinline__ float eval16_q(const char* fbl, const s16x8& Bty) {
    const f32x4 zc = {0.0f, 0.0f, 0.0f, 0.0f};
    f32x4 C[4];
#pragma unroll
    for (int t = 0; t < 4; ++t) {
        const s16x8 a  = *reinterpret_cast<const s16x8*>(fbl + FR_AIN(t) * 1024);
        const f32x4 bi = *reinterpret_cast<const f32x4*>(fbl + FR_BIN(t) * 1024);
        C[t] = __builtin_amdgcn_mfma_f32_16x16x32_bf16(a, Bty, bi, 0, 0, 0);
    }
    s16x8 B0, B1;
    trans16(C, B0, B1);
#pragma unroll
    for (int L = 0; L < 3; ++L) {
#pragma unroll
        for (int t = 0; t < 4; ++t) {
            const s16x8 a0 = *reinterpret_cast<const s16x8*>(fbl + FR_AH(L, t, 0) * 1024);
            const s16x8 a1 = *reinterpret_cast<const s16x8*>(fbl + FR_AH(L, t, 1) * 1024);
            const f32x4 bh = *reinterpret_cast<const f32x4*>(fbl + FR_BHD(L, t) * 1024);
            f32x4 c = __builtin_amdgcn_mfma_f32_16x16x32_bf16(a0, B0, bh, 0, 0, 0);
            C[t]    = __builtin_amdgcn_mfma_f32_16x16x32_bf16(a1, B1, c, 0, 0, 0);
        }
        trans16(C, B0, B1);
    }
    const s16x8 o0 = *reinterpret_cast<const s16x8*>(fbl + FR_AOUT(0) * 1024);
    const s16x8 o1 = *reinterpret_cast<const s16x8*>(fbl + FR_AOUT(1) * 1024);
    f32x4 Co = __builtin_amdgcn_mfma_f32_16x16x32_bf16(o0, B0, zc, 0, 0, 0);
    Co = __builtin_amdgcn_mfma_f32_16x16x32_bf16(o1, B1, Co, 0, 0, 0);
    return Co[0] + *reinterpret_cast<const float*>(fbl + FR_BOUT * 1024);
}

// ====================== the single fused kernel ======================

extern "C" __global__ void __launch_bounds__(1024, 4)
fbsnn_one(const float* __restrict__ Y_Win, const float* __restrict__ Y_bin,
          const float* __restrict__ Y_Whid, const float* __restrict__ Y_bhid,
          const float* __restrict__ Y_Wout, const float* __restrict__ Y_bout,
          const float* __restrict__ q_Win, const float* __restrict__ q_bin,
          const float* __restrict__ q_Whid, const float* __restrict__ q_bhid,
          const float* __restrict__ q_Wout, const float* __restrict__ q_bout,
          const float* __restrict__ y0p, const float* __restrict__ dW,
          float* __restrict__ ws, float* __restrict__ out)
{
    extern __shared__ __align__(16) float sf[];
    float* qg   = sf + L_QG;
    float* yb   = sf + L_YB;
    float* qb   = sf + L_QB;
    float* Yb   = sf + L_YY;
    float* dYb  = sf + L_DY;
    float* dWb  = sf + L_DW;
    float* part = sf + L_PART;
    int*   prog = (int*)(sf + L_PROG);

    int* done = (int*)ws;
    float* qgw = ws + WS_QG;
    unsigned long long* pairs = (unsigned long long*)(ws + WS_PAIR);

    const int tid = (int)threadIdx.x;
    const int wv  = tid >> 6;          // 0..15; wave 0 = scanner
    const int l   = tid & 63;
    const int qd  = l >> 4;
    const int m   = l & 15;
    const int blk = (int)blockIdx.x;

    if (tid == 0) *prog = 0;
    const float ylo = grid_ylo(y0p);
    const f32x4 zc  = {0.0f, 0.0f, 0.0f, 0.0f};

    // ---- phase A: local frag builds + dW staging ----
    if (wv < 4) {
        char* fbl = (char*)(sf + L_FR) + l * 16;
        build_sec(wv, Y_Win, Y_bin, Y_Whid, Y_bhid, Y_Wout, Y_bout, qd, m, fbl);
    } else if (wv < 8) {
        if (blk < 50) {
            char* fql = (char*)sf + l * 16;        // q-frags reuse qgrid LDS
            build_sec(wv - 4, q_Win, q_bin, q_Whid, q_bhid, q_Wout, q_bout, qd, m, fql);
        }
    } else {
        // waves 8-15: stage this block's dW rows (50x16 floats, 64B coalesced)
        for (int idx = tid - 512; idx < 800; idx += 512)
            dWb[idx] = dW[(idx >> 4) * NPATH + blk * 16 + (idx & 15)];
    }
    __syncthreads();

    // ---- phase A: q-grid tabulation (blocks 0..49; timestep n = blk) ----
    if (blk < 50) {
        const char* fql = (const char*)sf + l * 16;
        const float tt = blk * DT_F;
        const float yg = ylo + (float)(16 * wv + m) * GRID_DY;  // k/8: exact bf16
        const s16x8 Bty = frag4((qd == 0) ? pkbf(tt, yg) : 0u, 0u, 0u, 0u);
        const float qv = eval16_q(fql, Bty);
        if (qd == 0) qgw[blk * GRID_N + 16 * wv + m] = qv;
        __syncthreads();
        if (tid == 0) {
            __threadfence();   // release: L2 writeback of qgrid row
            __hip_atomic_store(&done[blk], (int)MAGIC, __ATOMIC_RELAXED,
                               __HIP_MEMORY_SCOPE_AGENT);
        }
    }

    // ---- device barrier: wait for all 50 grid rows (deadlock-free) ----
    if (wv == 0) {
        if (l < 50)
            while (__hip_atomic_load(&done[l], __ATOMIC_RELAXED,
                                     __HIP_MEMORY_SCOPE_AGENT) != (int)MAGIC)
                __builtin_amdgcn_s_sleep(8);
        __threadfence();       // acquire: L2 invalidate before staging reads
    }
    __syncthreads();

    // ---- stage 0: qgrid ws -> LDS (3200 x 16B, coalesced) ----
#pragma unroll
    for (int k = 0; k < 4; ++k) {
        const int idx = tid + k * 1024;
        if (idx < 3200)
            ((float4v*)qg)[idx] = ((const float4v*)qgw)[idx];
    }
    __syncthreads();

    // ---- phase B ----
    if (wv == 0) {
        // scan: Catmull-Rom interp on the q-grid. LDS-only loop: dW comes
        // from dWb, publish is a RELEASE LDS store (lgkmcnt drain only).
        float y = y0p[0];
        for (int n = 0; n < NSTEP; ++n) {
            if (l < 16) yb[n * 16 + m] = y;
            if (l == 0) __hip_atomic_store(prog, n + 1, __ATOMIC_RELEASE,
                                           __HIP_MEMORY_SCOPE_WORKGROUP);
            const float dwv = dWb[n * 16 + m];   // off the dependence chain

            float u = (y - ylo) * GRID_INV;
            u = fminf(fmaxf(u, 1.0f), 253.999f);
            int i = (int)u;
            if (i > 253) i = 253;
            const float fr = u - (float)i;
            const float* row = qg + n * GRID_N + i;
            const float q0 = row[-1], q1 = row[0], q2 = row[1], q3 = row[2];
            const float qt = q1 + 0.5f * fr * ((q2 - q0)
                           + fr * ((2.0f * q0 - 5.0f * q1 + 4.0f * q2 - q3)
                           + fr * (3.0f * (q1 - q2) + q3 - q0)));

            if (l < 16) qb[n * 16 + m] = qt;
            y = fmaf(qt, DT_F, y) + SIGMA_F * (dwv * SQRT_DT);
        }
        if (l < 16) yb[NSTEP * 16 + m] = y;
        if (l == 0) __hip_atomic_store(prog, NSTEP + 1, __ATOMIC_RELEASE,
                                       __HIP_MEMORY_SCOPE_WORKGROUP);
    } else {
        // consumers: rows (wv-1)+15j, j=0..2; waves 1..6 add 44+wv
        const char* fbl = (const char*)(sf + L_FR) + l * 16;
        const s16x8 Btn = frag4((qd == 0) ? pkbf(0.0f, 1.0f) : 0u, 0u, 0u, 0u);
        const float boutY = *reinterpret_cast<const float*>(fbl + FR_BOUT * 1024);

        const int cnt = (wv <= 6) ? 4 : 3;
        for (int j = 0; j < cnt; ++j) {
            const int k = (j < 3) ? (wv - 1) + 15 * j : 44 + wv;

            while (__hip_atomic_load(prog, __ATOMIC_ACQUIRE,
                                     __HIP_MEMORY_SCOPE_WORKGROUP) <= k)
                __builtin_amdgcn_s_sleep(2);

            const float yv = yb[k * 16 + m];
            const float tt = k * DT_F;
            const s16x8 Bty = frag4((qd == 0) ? pkbf(tt, yv) : 0u, 0u, 0u, 0u);

            f32x4 Cf[4], Ct[4];
#pragma unroll
            for (int t = 0; t < 4; ++t) {
                const s16x8 a  = *reinterpret_cast<const s16x8*>(fbl + FR_AIN(t) * 1024);
                const f32x4 bi = *reinterpret_cast<const f32x4*>(fbl + FR_BIN(t) * 1024);
                Cf[t] = __builtin_amdgcn_mfma_f32_16x16x32_bf16(a, Bty, bi, 0, 0, 0);
                Ct[t] = __builtin_amdgcn_mfma_f32_16x16x32_bf16(a, Btn, zc, 0, 0, 0);
            }
            s16x8 bf0, bf1, bt0, bt1;
            trans16t(Cf, Ct, bf0, bf1, bt0, bt1);

#pragma unroll
            for (int L = 0; L < 3; ++L) {
#pragma unroll
                for (int t = 0; t < 4; ++t) {
                    const s16x8 a0 = *reinterpret_cast<const s16x8*>(fbl + FR_AH(L, t, 0) * 1024);
                    const s16x8 a1 = *reinterpret_cast<const s16x8*>(fbl + FR_AH(L, t, 1) * 1024);
                    const f32x4 bh = *reinterpret_cast<const f32x4*>(fbl + FR_BHD(L, t) * 1024);
                    f32x4 c = __builtin_amdgcn_mfma_f32_16x16x32_bf16(a0, bf0, bh, 0, 0, 0);
                    Cf[t]   = __builtin_amdgcn_mfma_f32_16x16x32_bf16(a1, bf1, c, 0, 0, 0);
                    f32x4 z = __builtin_amdgcn_mfma_f32_16x16x32_bf16(a0, bt0, zc, 0, 0, 0);
                    Ct[t]   = __builtin_amdgcn_mfma_f32_16x16x32_bf16(a1, bt1, z, 0, 0, 0);
                }
                trans16t(Cf, Ct, bf0, bf1, bt0, bt1);
            }

            const s16x8 o0 = *reinterpret_cast<const s16x8*>(fbl + FR_AOUT(0) * 1024);
            const s16x8 o1 = *reinterpret_cast<const s16x8*>(fbl + FR_AOUT(1) * 1024);
            f32x4 Cof = __builtin_amdgcn_mfma_f32_16x16x32_bf16(o0, bf0, zc, 0, 0, 0);
            Cof = __builtin_amdgcn_mfma_f32_16x16x32_bf16(o1, bf1, Cof, 0, 0, 0);
            f32x4 Cot = __builtin_amdgcn_mfma_f32_16x16x32_bf16(o0, bt0, zc, 0, 0, 0);
            Cot = __builtin_amdgcn_mfma_f32_16x16x32_bf16(o1, bt1, Cot, 0, 0, 0);

            if (qd == 0) {
                Yb[k * 16 + m]  = Cof[0] + boutY;
                dYb[k * 16 + m] = Cot[0];
            }
        }
    }

    // ---- epilogue: residuals + per-block reduction (dW from LDS) ----
    __syncthreads();

    float acc = 0.0f;
    if (tid < 816) {
        const int it = tid;
        if (it < 800) {
            const float q    = qb[it];
            const float dYc  = dYb[it];
            const float Yn   = Yb[it];
            const float Yn1  = Yb[it + 16];
            const float dws  = dWb[it] * SQRT_DT;
            const float Ytil = fmaf(-q * q, DT_F, Yn) + (SIGMA_F * dYc) * dws;
            const float r    = Yn1 - Ytil;
            acc = fmaf(r, r, acc);
        } else {
            const int pp = it - 800;
            const float y50  = yb[NSTEP * 16 + pp];
            const float Y50  = Yb[NSTEP * 16 + pp];
            const float dY50 = dYb[NSTEP * 16 + pp];
            const float r1 = Y50 - y50 * y50;
            const float r2 = dY50 - 2.0f * y50;
            acc = fmaf(r1, r1, fmaf(r2, r2, acc));
        }
    }
#pragma unroll
    for (int off = 32; off > 0; off >>= 1) acc += __shfl_down(acc, off, 64);
    if (l == 0) part[wv] = acc;
    __syncthreads();

    // ---- cross-block reduction via {MAGIC,float} sentinel pairs ----
    if (wv == 0) {
        if (l == 0) {
            float bsum = 0.0f;
#pragma unroll
            for (int w = 0; w < 16; ++w) bsum += part[w];
            const unsigned long long pv =
                ((unsigned long long)MAGIC << 32) |
                (unsigned long long)__float_as_uint(bsum);
            __hip_atomic_store(&pairs[blk], pv, __ATOMIC_RELAXED,
                               __HIP_MEMORY_SCOPE_AGENT);
        }
        if (blk == 0) {
            float s = 0.0f;
#pragma unroll
            for (int r = 0; r < 4; ++r) {
                unsigned long long v;
                while ((unsigned)((v = __hip_atomic_load(&pairs[4 * l + r],
                                __ATOMIC_RELAXED, __HIP_MEMORY_SCOPE_AGENT)) >> 32)
                       != MAGIC)
                    __builtin_amdgcn_s_sleep(4);
                s += __uint_as_float((unsigned)(v & 0xffffffffu));
            }
#pragma unroll
            for (int off = 32; off > 0; off >>= 1) s += __shfl_down(s, off, 64);
            if (l == 0) out[0] = s * (1.0f / (float)NPATH);
        }
    }
}

// ================= host launch =================

extern "C" void kernel_launch(void* const* d_in, const int* in_sizes, int n_in,
                              void* d_out, int out_size, void* d_ws, size_t ws_size,
                              hipStream_t stream)
{
    const float* Y_Win  = (const float*)d_in[0];
    const float* Y_bin  = (const float*)d_in[1];
    const float* Y_Whid = (const float*)d_in[2];
    const float* Y_bhid = (const float*)d_in[3];
    const float* Y_Wout = (const float*)d_in[4];
    const float* Y_bout = (const float*)d_in[5];
    const float* q_Win  = (const float*)d_in[6];
    const float* q_bin  = (const float*)d_in[7];
    const float* q_Whid = (const float*)d_in[8];
    const float* q_bhid = (const float*)d_in[9];
    const float* q_Wout = (const float*)d_in[10];
    const float* q_bout = (const float*)d_in[11];
    const float* y0p    = (const float*)d_in[12];
    const float* dW     = (const float*)d_in[13];

    fbsnn_one<<<dim3(NPATH / 16), dim3(1024), SMEM_BYTES, stream>>>(
        Y_Win, Y_bin, Y_Whid, Y_bhid, Y_Wout, Y_bout,
        q_Win, q_bin, q_Whid, q_bhid, q_Wout, q_bout,
        y0p, dW, (float*)d_ws, (float*)d_out);
}

// Round 5
// 110.862 us; speedup vs baseline: 1.0955x; 1.0800x over previous
//
#include <hip/hip_runtime.h>

// FBSNN loss — single dispatch, EVERYTHING tabulated on the y-grid.
//
// Round 20: r18/r19's 13,056 redundant Y+tangent evals (51 per block; the
// issue-volume bottleneck: ~128 quarter-rate sin/cos + 60 MFMA each) are
// replaced by 816 grid evals TOTAL (16x less): Y(t_n,y) and dY/dy(t_n,y)
// are scalar functions of y, so they are tabulated on the same 256-node
// y-grid as q and Catmull-Rom-interpolated per path.
//   Phase A: blocks 0..49  : q-net frags -> LDS, tabulate q(t_n, grid) (16
//                            waves x 16 cols), store row, fence, sentinel.
//            blocks 64..114: Y-net frags -> LDS, tabulate Y+dY (tangent)
//                            rows n=blk-64 in [0,50], fence, sentinel.
//   Barrier: wave 0 spins on the 101 sentinels (poison/replay-proof:
//            writers never wait), acquire threadfence, syncthreads.
//   Stage:   all 3 grids (38912 floats, contiguous) ws -> LDS, coalesced.
//   Phase B: waves 1-15 EXIT. Wave 0: 50-step scan for 32 paths with
//            q/Y/dY interp + inline residual accumulation. No MFMA, no
//            spins, no publishes — pure LDS+VALU loop (~300 cyc/step).
//   Reduce:  per-block {MAGIC,float} pair; block 0 gathers 128 pairs.
// q-grid math identical to r16-r19 (same build/eval/interp) -> trajectory
// bitwise identical; Y/dY now interped (error ~1e-4 << bf16 noise).

#define NPATH   4096
#define NSTEP   50
#define DT_F    0.02f
#define SQRT_DT 0.14142136f
#define SIGMA_F 0.5f
#define INV2PI  0.15915494309189535f
#define TWOPI_F 6.28318530717958648f

#define GRID_N   256
#define GRID_INV 8.0f
#define GRID_DY  0.125f

#define NBLK    128
#define PPB     32                          // paths per block

#define QG_FLOATS  (NSTEP * GRID_N)         // 12800
#define YG_FLOATS  ((NSTEP + 1) * GRID_N)   // 13056

#define MAGIC 0x5AB1C0DEu

// fragment ids (16B per lane each)
#define FR_AIN(t)     (t)
#define FR_AH(L,t,kk) (4 + (L)*8 + (t)*2 + (kk))
#define FR_AOUT(kk)   (28 + (kk))
#define FR_BIN(t)     (30 + (t))
#define FR_BHD(L,t)   (34 + (L)*4 + (t))
#define FR_BOUT       46

// workspace layout (float offsets)
#define WS_DONE 0                           // 128 ints (sentinel per block id)
#define WS_QG   128                         // 12800
#define WS_YG   (WS_QG + QG_FLOATS)         // 12928
#define WS_DYG  (WS_YG + YG_FLOATS)         // 25984
#define WS_PAIR (WS_DYG + YG_FLOATS)        // 39040: 128 x {MAGIC,float} u64

// LDS layout (float offsets) — grids contiguous for one-shot staging
#define L_QG    0                           // phase A: q-frag build area
#define L_YG    QG_FLOATS                   // 12800; phase A: Y-frag build area
#define L_DYG   (L_YG + YG_FLOATS)          // 25856
#define SMEM_FLOATS (L_DYG + YG_FLOATS)     // 38912
#define SMEM_BYTES  (SMEM_FLOATS * 4)       // 155,648 B

typedef __attribute__((ext_vector_type(8)))  short s16x8;
typedef __attribute__((ext_vector_type(4)))  float f32x4;
typedef __attribute__((ext_vector_type(4)))  float float4v;

#if __has_builtin(__builtin_amdgcn_cvt_pk_bf16_f32)
__device__ __forceinline__ unsigned pkbf(float a, float b) {
    auto r = __builtin_amdgcn_cvt_pk_bf16_f32(a, b);
    unsigned u; __builtin_memcpy(&u, &r, 4); return u;
}
#else
__device__ __forceinline__ unsigned pkbf(float a, float b) {
    unsigned ua = __float_as_uint(a), ub = __float_as_uint(b);
    ua += 0x7fffu + ((ua >> 16) & 1u);
    ub += 0x7fffu + ((ub >> 16) & 1u);
    return (ua >> 16) | (ub & 0xffff0000u);
}
#endif

__device__ __forceinline__ s16x8 frag4(unsigned a, unsigned b, unsigned c, unsigned d) {
    union { unsigned u[4]; s16x8 s; } x;
    x.u[0] = a; x.u[1] = b; x.u[2] = c; x.u[3] = d;
    return x.s;
}

__device__ __forceinline__ float sinrev(float x) {
#if __has_builtin(__builtin_amdgcn_sinf)
    return __builtin_amdgcn_sinf(x);
#else
    return __sinf(x * TWOPI_F);
#endif
}
__device__ __forceinline__ float cosrev(float x) {
#if __has_builtin(__builtin_amdgcn_cosf)
    return __builtin_amdgcn_cosf(x);
#else
    return __cosf(x * TWOPI_F);
#endif
}

__device__ __forceinline__ int slot16(int t, int r) {
    return (t < 2) ? 8 * (r >> 2) + 4 * t + (r & 3)
                   : 32 + 8 * (r >> 2) + 4 * (t - 2) + (r & 3);
}

// Build one section of a net's fragments straight into LDS.
__device__ __forceinline__ void build_sec(
    int sec, const float* __restrict__ Win, const float* __restrict__ bin,
    const float* __restrict__ Whid, const float* __restrict__ bhid,
    const float* __restrict__ Wout, const float* __restrict__ bo,
    int qd, int m, char* fbl)
{
    if (sec == 0) {
#pragma unroll
        for (int t = 0; t < 4; ++t) {
            const int uo = slot16(t, m);
            unsigned w0 = 0;
            if (qd == 0) w0 = pkbf(INV2PI * Win[uo], INV2PI * Win[64 + uo]);
            *reinterpret_cast<s16x8*>(fbl + FR_AIN(t) * 1024) = frag4(w0, 0u, 0u, 0u);
            f32x4 bi;
#pragma unroll
            for (int i = 0; i < 4; ++i) bi[i] = INV2PI * bin[slot16(t, 4 * qd + i)];
            *reinterpret_cast<f32x4*>(fbl + FR_BIN(t) * 1024) = bi;
        }
#pragma unroll
        for (int kk = 0; kk < 2; ++kk) {
            unsigned w[4] = {0u, 0u, 0u, 0u};
            if (m == 0) {
#pragma unroll
                for (int j2 = 0; j2 < 4; ++j2) {
                    int e0 = 32 * kk + 8 * qd + 2 * j2;
                    w[j2] = pkbf(Wout[e0], Wout[e0 + 1]);
                }
            }
            *reinterpret_cast<s16x8*>(fbl + FR_AOUT(kk) * 1024) = frag4(w[0], w[1], w[2], w[3]);
        }
        f32x4 bo4 = {bo[0], 0.0f, 0.0f, 0.0f};
        *reinterpret_cast<f32x4*>(fbl + FR_BOUT * 1024) = bo4;
    } else {
        const int L = sec - 1;
#pragma unroll
        for (int t = 0; t < 4; ++t) {
            const int uo = slot16(t, m);
            const float* W = Whid + L * 4096 + uo;
#pragma unroll
            for (int kk = 0; kk < 2; ++kk) {
                unsigned w[4];
#pragma unroll
                for (int j2 = 0; j2 < 4; ++j2) {
                    int e0 = 32 * kk + 8 * qd + 2 * j2;
                    w[j2] = pkbf(INV2PI * W[e0 * 64], INV2PI * W[(e0 + 1) * 64]);
                }
                *reinterpret_cast<s16x8*>(fbl + FR_AH(L, t, kk) * 1024) = frag4(w[0], w[1], w[2], w[3]);
            }
            f32x4 bh;
#pragma unroll
            for (int i = 0; i < 4; ++i) bh[i] = INV2PI * bhid[L * 64 + slot16(t, 4 * qd + i)];
            *reinterpret_cast<f32x4*>(fbl + FR_BHD(L, t) * 1024) = bh;
        }
    }
}

__device__ __forceinline__ void trans16(const f32x4* C, s16x8& B0, s16x8& B1) {
    float a[4][4];
#pragma unroll
    for (int t = 0; t < 4; ++t)
#pragma unroll
        for (int i = 0; i < 4; ++i) a[t][i] = sinrev(C[t][i]);
    B0 = frag4(pkbf(a[0][0], a[0][1]), pkbf(a[0][2], a[0][3]),
               pkbf(a[1][0], a[1][1]), pkbf(a[1][2], a[1][3]));
    B1 = frag4(pkbf(a[2][0], a[2][1]), pkbf(a[2][2], a[2][3]),
               pkbf(a[3][0], a[3][1]), pkbf(a[3][2], a[3][3]));
}

__device__ __forceinline__ void trans16t(const f32x4* Cf, const f32x4* Ct,
                                         s16x8& Bf0, s16x8& Bf1,
                                         s16x8& Bt0, s16x8& Bt1)
{
    float s[4][4], d[4][4];
#pragma unroll
    for (int t = 0; t < 4; ++t)
#pragma unroll
        for (int i = 0; i < 4; ++i) {
            float cf = Cf[t][i];
            s[t][i] = sinrev(cf);
            d[t][i] = cosrev(cf) * (TWOPI_F * Ct[t][i]);
        }
    Bf0 = frag4(pkbf(s[0][0], s[0][1]), pkbf(s[0][2], s[0][3]),
                pkbf(s[1][0], s[1][1]), pkbf(s[1][2], s[1][3]));
    Bf1 = frag4(pkbf(s[2][0], s[2][1]), pkbf(s[2][2], s[2][3]),
                pkbf(s[3][0], s[3][1]), pkbf(s[3][2], s[3][3]));
    Bt0 = frag4(pkbf(d[0][0], d[0][1]), pkbf(d[0][2], d[0][3]),
                pkbf(d[1][0], d[1][1]), pkbf(d[1][2], d[1][3]));
    Bt1 = frag4(pkbf(d[2][0], d[2][1]), pkbf(d[2][2], d[2][3]),
                pkbf(d[3][0], d[3][1]), pkbf(d[3][2], d[3][3]));
}

__device__ __forceinline__ float grid_ylo(const float* __restrict__ y0p) {
    return floorf(y0p[0] * 8.0f) * 0.125f - 16.0f;
}

// forward-only eval (q-grid), frags from LDS at fbl = base + l*16
__device__ __forceinline__ float eval16_q(const char* fbl, const s16x8& Bty) {
    const f32x4 zc = {0.0f, 0.0f, 0.0f, 0.0f};
    f32x4 C[4];
#pragma unroll
    for (int t = 0; t < 4; ++t) {
        const s16x8 a  = *reinterpret_cast<const s16x8*>(fbl + FR_AIN(t) * 1024);
        const f32x4 bi = *reinterpret_cast<const f32x4*>(fbl + FR_BIN(t) * 1024);
        C[t] = __builtin_amdgcn_mfma_f32_16x16x32_bf16(a, Bty, bi, 0, 0, 0);
    }
    s16x8 B0, B1;
    trans16(C, B0, B1);
#pragma unroll
    for (int L = 0; L < 3; ++L) {
#pragma unroll
        for (int t = 0; t < 4; ++t) {
            const s16x8 a0 = *reinterpret_cast<const s16x8*>(fbl + FR_AH(L, t, 0) * 1024);
            const s16x8 a1 = *reinterpret_cast<const s16x8*>(fbl + FR_AH(L, t, 1) * 1024);
            const f32x4 bh = *reinterpret_cast<const f32x4*>(fbl + FR_BHD(L, t) * 1024);
            f32x4 c = __builtin_amdgcn_mfma_f32_16x16x32_bf16(a0, B0, bh, 0, 0, 0);
            C[t]    = __builtin_amdgcn_mfma_f32_16x16x32_bf16(a1, B1, c, 0, 0, 0);
        }
        trans16(C, B0, B1);
    }
    const s16x8 o0 = *reinterpret_cast<const s16x8*>(fbl + FR_AOUT(0) * 1024);
    const s16x8 o1 = *reinterpret_cast<const s16x8*>(fbl + FR_AOUT(1) * 1024);
    f32x4 Co = __builtin_amdgcn_mfma_f32_16x16x32_bf16(o0, B0, zc, 0, 0, 0);
    Co = __builtin_amdgcn_mfma_f32_16x16x32_bf16(o1, B1, Co, 0, 0, 0);
    return Co[0] + *reinterpret_cast<const float*>(fbl + FR_BOUT * 1024);
}

// fwd + tangent eval (Y-grid): returns Y and dY/dy at the 16 cols
__device__ __forceinline__ void eval16t(const char* fbl, const s16x8& Bty,
                                        const s16x8& Btn, float& Yv, float& dYv) {
    const f32x4 zc = {0.0f, 0.0f, 0.0f, 0.0f};
    f32x4 Cf[4], Ct[4];
#pragma unroll
    for (int t = 0; t < 4; ++t) {
        const s16x8 a  = *reinterpret_cast<const s16x8*>(fbl + FR_AIN(t) * 1024);
        const f32x4 bi = *reinterpret_cast<const f32x4*>(fbl + FR_BIN(t) * 1024);
        Cf[t] = __builtin_amdgcn_mfma_f32_16x16x32_bf16(a, Bty, bi, 0, 0, 0);
        Ct[t] = __builtin_amdgcn_mfma_f32_16x16x32_bf16(a, Btn, zc, 0, 0, 0);
    }
    s16x8 bf0, bf1, bt0, bt1;
    trans16t(Cf, Ct, bf0, bf1, bt0, bt1);
#pragma unroll
    for (int L = 0; L < 3; ++L) {
#pragma unroll
        for (int t = 0; t < 4; ++t) {
            const s16x8 a0 = *reinterpret_cast<const s16x8*>(fbl + FR_AH(L, t, 0) * 1024);
            const s16x8 a1 = *reinterpret_cast<const s16x8*>(fbl + FR_AH(L, t, 1) * 1024);
            const f32x4 bh = *reinterpret_cast<const f32x4*>(fbl + FR_BHD(L, t) * 1024);
            f32x4 c = __builtin_amdgcn_mfma_f32_16x16x32_bf16(a0, bf0, bh, 0, 0, 0);
            Cf[t]   = __builtin_amdgcn_mfma_f32_16x16x32_bf16(a1, bf1, c, 0, 0, 0);
            f32x4 z = __builtin_amdgcn_mfma_f32_16x16x32_bf16(a0, bt0, zc, 0, 0, 0);
            Ct[t]   = __builtin_amdgcn_mfma_f32_16x16x32_bf16(a1, bt1, z, 0, 0, 0);
        }
        trans16t(Cf, Ct, bf0, bf1, bt0, bt1);
    }
    const s16x8 o0 = *reinterpret_cast<const s16x8*>(fbl + FR_AOUT(0) * 1024);
    const s16x8 o1 = *reinterpret_cast<const s16x8*>(fbl + FR_AOUT(1) * 1024);
    f32x4 Cof = __builtin_amdgcn_mfma_f32_16x16x32_bf16(o0, bf0, zc, 0, 0, 0);
    Cof = __builtin_amdgcn_mfma_f32_16x16x32_bf16(o1, bf1, Cof, 0, 0, 0);
    f32x4 Cot = __builtin_amdgcn_mfma_f32_16x16x32_bf16(o0, bt0, zc, 0, 0, 0);
    Cot = __builtin_amdgcn_mfma_f32_16x16x32_bf16(o1, bt1, Cot, 0, 0, 0);
    Yv  = Cof[0] + *reinterpret_cast<const float*>(fbl + FR_BOUT * 1024);
    dYv = Cot[0];
}

// Catmull-Rom (identical formula to r16-r19's q interp)
__device__ __forceinline__ float cmr(const float* row, float fr) {
    const float q0 = row[-1], q1 = row[0], q2 = row[1], q3 = row[2];
    return q1 + 0.5f * fr * ((q2 - q0)
             + fr * ((2.0f * q0 - 5.0f * q1 + 4.0f * q2 - q3)
             + fr * (3.0f * (q1 - q2) + q3 - q0)));
}

// ====================== the single fused kernel ======================

extern "C" __global__ void __launch_bounds__(1024, 4)
fbsnn_one(const float* __restrict__ Y_Win, const float* __restrict__ Y_bin,
          const float* __restrict__ Y_Whid, const float* __restrict__ Y_bhid,
          const float* __restrict__ Y_Wout, const float* __restrict__ Y_bout,
          const float* __restrict__ q_Win, const float* __restrict__ q_bin,
          const float* __restrict__ q_Whid, const float* __restrict__ q_bhid,
          const float* __restrict__ q_Wout, const float* __restrict__ q_bout,
          const float* __restrict__ y0p, const float* __restrict__ dW,
          float* __restrict__ ws, float* __restrict__ out)
{
    extern __shared__ __align__(16) float sf[];
    float* qg  = sf + L_QG;
    float* Yg  = sf + L_YG;
    float* dYg = sf + L_DYG;

    int* done = (int*)ws;
    unsigned long long* pairs = (unsigned long long*)(ws + WS_PAIR);

    const int tid = (int)threadIdx.x;
    const int wv  = tid >> 6;
    const int l   = tid & 63;
    const int qd  = l >> 4;            // grid-eval lane decomposition
    const int mm  = l & 15;
    const int blk = (int)blockIdx.x;

    const bool is_q = (blk < NSTEP);                       // rows 0..49
    const bool is_y = (blk >= 64 && blk < 64 + NSTEP + 1); // rows 0..50

    const float ylo = grid_ylo(y0p);

    // ---- phase A: frag build (waves 0-3 of grid blocks) ----
    if (wv < 4) {
        if (is_q)
            build_sec(wv, q_Win, q_bin, q_Whid, q_bhid, q_Wout, q_bout, qd, mm,
                      (char*)(sf + L_QG) + l * 16);
        else if (is_y)
            build_sec(wv, Y_Win, Y_bin, Y_Whid, Y_bhid, Y_Wout, Y_bout, qd, mm,
                      (char*)(sf + L_YG) + l * 16);
    }
    __syncthreads();                                       // B1

    // ---- phase A: grid tabulation (one row per grid block, 16 waves) ----
    if (is_q) {
        const char* fbl = (const char*)(sf + L_QG) + l * 16;
        const float tt = blk * DT_F;
        const float yg = ylo + (float)(16 * wv + mm) * GRID_DY;  // k/8 exact bf16
        const s16x8 Bty = frag4((qd == 0) ? pkbf(tt, yg) : 0u, 0u, 0u, 0u);
        const float qv = eval16_q(fbl, Bty);
        if (qd == 0) ws[WS_QG + blk * GRID_N + 16 * wv + mm] = qv;
    } else if (is_y) {
        const char* fbl = (const char*)(sf + L_YG) + l * 16;
        const int   n   = blk - 64;
        const float tt  = n * DT_F;
        const float yg  = ylo + (float)(16 * wv + mm) * GRID_DY;
        const s16x8 Bty = frag4((qd == 0) ? pkbf(tt, yg) : 0u, 0u, 0u, 0u);
        const s16x8 Btn = frag4((qd == 0) ? pkbf(0.0f, 1.0f) : 0u, 0u, 0u, 0u);
        float Yv, dYv;
        eval16t(fbl, Bty, Btn, Yv, dYv);
        if (qd == 0) {
            ws[WS_YG  + n * GRID_N + 16 * wv + mm] = Yv;
            ws[WS_DYG + n * GRID_N + 16 * wv + mm] = dYv;
        }
    }
    __syncthreads();                                       // B2

    if ((is_q || is_y) && tid == 0) {
        __threadfence();   // release: L2 writeback of this block's rows
        __hip_atomic_store(&done[blk], (int)MAGIC, __ATOMIC_RELAXED,
                           __HIP_MEMORY_SCOPE_AGENT);
    }

    // ---- device barrier: wave 0 spins on the 101 sentinels ----
    if (wv == 0) {
        if (l < NSTEP)          // q rows: slots 0..49
            while (__hip_atomic_load(&done[l], __ATOMIC_RELAXED,
                                     __HIP_MEMORY_SCOPE_AGENT) != (int)MAGIC)
                __builtin_amdgcn_s_sleep(8);
        if (l < NSTEP + 1)      // Y rows: slots 64..114
            while (__hip_atomic_load(&done[64 + l], __ATOMIC_RELAXED,
                                     __HIP_MEMORY_SCOPE_AGENT) != (int)MAGIC)
                __builtin_amdgcn_s_sleep(8);
        __threadfence();        // acquire: invalidate before staging reads
    }
    __syncthreads();                                       // B3

    // ---- stage: all 3 grids ws -> LDS (9728 x 16B, coalesced) ----
#pragma unroll
    for (int k = 0; k < 10; ++k) {
        const int idx = tid + k * 1024;
        if (idx < (SMEM_FLOATS / 4))
            ((float4v*)sf)[idx] = ((const float4v*)(ws + WS_QG))[idx];
    }
    __syncthreads();                                       // B4

    if (wv != 0) return;       // waves 1-15 done (no further barriers)

    // ---- phase B: scan + interp + inline residuals (wave 0 only) ----
    const int m = l & (PPB - 1);           // path within block (lanes 32-63 dup)
    const int p = blk * PPB + m;

    float y   = y0p[0];
    float acc = 0.0f;
    float Yp = 0.0f, dYp = 0.0f, qp = 0.0f, dwp = 0.0f;
    float dwv = dW[p];

    for (int n = 0; n < NSTEP; ++n) {
        const float dw_next = (n + 1 < NSTEP) ? dW[(n + 1) * NPATH + p] : 0.0f;

        float u = (y - ylo) * GRID_INV;
        u = fminf(fmaxf(u, 1.0f), 253.999f);
        int i = (int)u;
        if (i > 253) i = 253;
        const float fr = u - (float)i;

        const float qn  = cmr(qg  + n * GRID_N + i, fr);
        const float Yn  = cmr(Yg  + n * GRID_N + i, fr);
        const float dYn = cmr(dYg + n * GRID_N + i, fr);

        if (n) {   // residual for step n-1: Y_n vs Y_tilde(n-1)
            const float r = Yn - (fmaf(-qp * qp, DT_F, Yp)
                                  + (SIGMA_F * dYp) * (dwp * SQRT_DT));
            acc = fmaf(r, r, acc);
        }
        qp = qn; Yp = Yn; dYp = dYn; dwp = dwv;
        y = fmaf(qn, DT_F, y) + SIGMA_F * (dwv * SQRT_DT);
        dwv = dw_next;
    }
    {   // terminal row 50: last residual + terminal costs
        float u = (y - ylo) * GRID_INV;
        u = fminf(fmaxf(u, 1.0f), 253.999f);
        int i = (int)u;
        if (i > 253) i = 253;
        const float fr = u - (float)i;
        const float Y50  = cmr(Yg  + NSTEP * GRID_N + i, fr);
        const float dY50 = cmr(dYg + NSTEP * GRID_N + i, fr);
        const float r = Y50 - (fmaf(-qp * qp, DT_F, Yp)
                               + (SIGMA_F * dYp) * (dwp * SQRT_DT));
        acc = fmaf(r, r, acc);
        const float r1 = Y50 - y * y;
        const float r2 = dY50 - 2.0f * y;
        acc = fmaf(r1, r1, fmaf(r2, r2, acc));
    }
    if (l >= PPB) acc = 0.0f;              // drop duplicated lanes

#pragma unroll
    for (int off = 32; off > 0; off >>= 1) acc += __shfl_down(acc, off, 64);

    // ---- cross-block reduction via {MAGIC,float} sentinel pairs ----
    if (l == 0) {
        const unsigned long long pv =
            ((unsigned long long)MAGIC << 32) |
            (unsigned long long)__float_as_uint(acc);
        __hip_atomic_store(&pairs[blk], pv, __ATOMIC_RELAXED,
                           __HIP_MEMORY_SCOPE_AGENT);
    }
    if (blk == 0) {
        float s = 0.0f;
#pragma unroll
        for (int r = 0; r < 2; ++r) {
            unsigned long long v;
            while ((unsigned)((v = __hip_atomic_load(&pairs[64 * r + l],
                            __ATOMIC_RELAXED, __HIP_MEMORY_SCOPE_AGENT)) >> 32)
                   != MAGIC)
                __builtin_amdgcn_s_sleep(4);
            s += __uint_as_float((unsigned)(v & 0xffffffffu));
        }
#pragma unroll
        for (int off = 32; off > 0; off >>= 1) s += __shfl_down(s, off, 64);
        if (l == 0) out[0] = s * (1.0f / (float)NPATH);
    }
}

// ================= host launch =================

extern "C" void kernel_launch(void* const* d_in, const int* in_sizes, int n_in,
                              void* d_out, int out_size, void* d_ws, size_t ws_size,
                              hipStream_t stream)
{
    const float* Y_Win  = (const float*)d_in[0];
    const float* Y_bin  = (const float*)d_in[1];
    const float* Y_Whid = (const float*)d_in[2];
    const float* Y_bhid = (const float*)d_in[3];
    const float* Y_Wout = (const float*)d_in[4];
    const float* Y_bout = (const float*)d_in[5];
    const float* q_Win  = (const float*)d_in[6];
    const float* q_bin  = (const float*)d_in[7];
    const float* q_Whid = (const float*)d_in[8];
    const float* q_bhid = (const float*)d_in[9];
    const float* q_Wout = (const float*)d_in[10];
    const float* q_bout = (const float*)d_in[11];
    const float* y0p    = (const float*)d_in[12];
    const float* dW     = (const float*)d_in[13];

    fbsnn_one<<<dim3(NBLK), dim3(1024), SMEM_BYTES, stream>>>(
        Y_Win, Y_bin, Y_Whid, Y_bhid, Y_Wout, Y_bout,
        q_Win, q_bin, q_Whid, q_bhid, q_Wout, q_bout,
        y0p, dW, (float*)d_ws, (float*)d_out);
}

// Round 6
// 104.601 us; speedup vs baseline: 1.1611x; 1.0599x over previous
//
#include <hip/hip_runtime.h>

// FBSNN loss — single dispatch, everything tabulated on the y-grid.
//
// Round 21 = round 20 + dW staged to LDS (the scan loop's 1-deep global dW
// prefetch was L2-cold every iteration — the 256 MiB harness fill thrashes
// L2 — exposing ~300-600 cyc/step on the single scan wave, ~8-15 us).
// Waves 8-15 (idle in phase A) stage the block's 50x32 dW slab into LDS,
// overlapped with frag build + grid eval. Phase B now has ZERO global
// memory ops in the scan loop. LDS 155,648 -> 162,048 B (< 163,840 limit).
//
// Structure (unchanged from r20):
//   Phase A: blocks 0..49  : q-net frags -> LDS, tabulate q(t_n, grid).
//            blocks 64..114: Y-net frags -> LDS, tabulate Y+dY rows.
//            waves 8-15 everywhere: stage dW slab -> LDS.
//            producers: store row to ws, release fence, MAGIC sentinel
//            (poison/replay-proof; writers never wait).
//   Barrier: wave 0 spins on 101 sentinels, acquire fence, syncthreads.
//   Stage:   3 grids (38912 floats) ws -> LDS, coalesced float4.
//   Phase B: waves 1-15 exit. Wave 0: 50-step scan for 32 paths, q/Y/dY
//            Catmull-Rom interp + inline residuals — pure LDS+VALU loop.
//   Reduce:  per-block {MAGIC,float} pair; block 0 gathers 128 pairs.

#define NPATH   4096
#define NSTEP   50
#define DT_F    0.02f
#define SQRT_DT 0.14142136f
#define SIGMA_F 0.5f
#define INV2PI  0.15915494309189535f
#define TWOPI_F 6.28318530717958648f

#define GRID_N   256
#define GRID_INV 8.0f
#define GRID_DY  0.125f

#define NBLK    128
#define PPB     32                          // paths per block

#define QG_FLOATS  (NSTEP * GRID_N)         // 12800
#define YG_FLOATS  ((NSTEP + 1) * GRID_N)   // 13056

#define MAGIC 0x5AB1C0DEu

// fragment ids (16B per lane each)
#define FR_AIN(t)     (t)
#define FR_AH(L,t,kk) (4 + (L)*8 + (t)*2 + (kk))
#define FR_AOUT(kk)   (28 + (kk))
#define FR_BIN(t)     (30 + (t))
#define FR_BHD(L,t)   (34 + (L)*4 + (t))
#define FR_BOUT       46

// workspace layout (float offsets)
#define WS_DONE 0                           // 128 ints (sentinel per block id)
#define WS_QG   128                         // 12800
#define WS_YG   (WS_QG + QG_FLOATS)         // 12928
#define WS_DYG  (WS_YG + YG_FLOATS)         // 25984
#define WS_PAIR (WS_DYG + YG_FLOATS)        // 39040: 128 x {MAGIC,float} u64

// LDS layout (float offsets) — grids contiguous for one-shot staging
#define L_QG    0                           // phase A: q-frag build area
#define L_YG    QG_FLOATS                   // 12800; phase A: Y-frag build area
#define L_DYG   (L_YG + YG_FLOATS)          // 25856
#define L_DW    (L_DYG + YG_FLOATS)         // 38912  (50*32 dW slab)
#define SMEM_FLOATS (L_DW + NSTEP * PPB)    // 40512
#define SMEM_BYTES  (SMEM_FLOATS * 4)       // 162,048 B  (<= 163,840)

typedef __attribute__((ext_vector_type(8)))  short s16x8;
typedef __attribute__((ext_vector_type(4)))  float f32x4;
typedef __attribute__((ext_vector_type(4)))  float float4v;

#if __has_builtin(__builtin_amdgcn_cvt_pk_bf16_f32)
__device__ __forceinline__ unsigned pkbf(float a, float b) {
    auto r = __builtin_amdgcn_cvt_pk_bf16_f32(a, b);
    unsigned u; __builtin_memcpy(&u, &r, 4); return u;
}
#else
__device__ __forceinline__ unsigned pkbf(float a, float b) {
    unsigned ua = __float_as_uint(a), ub = __float_as_uint(b);
    ua += 0x7fffu + ((ua >> 16) & 1u);
    ub += 0x7fffu + ((ub >> 16) & 1u);
    return (ua >> 16) | (ub & 0xffff0000u);
}
#endif

__device__ __forceinline__ s16x8 frag4(unsigned a, unsigned b, unsigned c, unsigned d) {
    union { unsigned u[4]; s16x8 s; } x;
    x.u[0] = a; x.u[1] = b; x.u[2] = c; x.u[3] = d;
    return x.s;
}

__device__ __forceinline__ float sinrev(float x) {
#if __has_builtin(__builtin_amdgcn_sinf)
    return __builtin_amdgcn_sinf(x);
#else
    return __sinf(x * TWOPI_F);
#endif
}
__device__ __forceinline__ float cosrev(float x) {
#if __has_builtin(__builtin_amdgcn_cosf)
    return __builtin_amdgcn_cosf(x);
#else
    return __cosf(x * TWOPI_F);
#endif
}

__device__ __forceinline__ int slot16(int t, int r) {
    return (t < 2) ? 8 * (r >> 2) + 4 * t + (r & 3)
                   : 32 + 8 * (r >> 2) + 4 * (t - 2) + (r & 3);
}

// Build one section of a net's fragments straight into LDS.
__device__ __forceinline__ void build_sec(
    int sec, const float* __restrict__ Win, const float* __restrict__ bin,
    const float* __restrict__ Whid, const float* __restrict__ bhid,
    const float* __restrict__ Wout, const float* __restrict__ bo,
    int qd, int m, char* fbl)
{
    if (sec == 0) {
#pragma unroll
        for (int t = 0; t < 4; ++t) {
            const int uo = slot16(t, m);
            unsigned w0 = 0;
            if (qd == 0) w0 = pkbf(INV2PI * Win[uo], INV2PI * Win[64 + uo]);
            *reinterpret_cast<s16x8*>(fbl + FR_AIN(t) * 1024) = frag4(w0, 0u, 0u, 0u);
            f32x4 bi;
#pragma unroll
            for (int i = 0; i < 4; ++i) bi[i] = INV2PI * bin[slot16(t, 4 * qd + i)];
            *reinterpret_cast<f32x4*>(fbl + FR_BIN(t) * 1024) = bi;
        }
#pragma unroll
        for (int kk = 0; kk < 2; ++kk) {
            unsigned w[4] = {0u, 0u, 0u, 0u};
            if (m == 0) {
#pragma unroll
                for (int j2 = 0; j2 < 4; ++j2) {
                    int e0 = 32 * kk + 8 * qd + 2 * j2;
                    w[j2] = pkbf(Wout[e0], Wout[e0 + 1]);
                }
            }
            *reinterpret_cast<s16x8*>(fbl + FR_AOUT(kk) * 1024) = frag4(w[0], w[1], w[2], w[3]);
        }
        f32x4 bo4 = {bo[0], 0.0f, 0.0f, 0.0f};
        *reinterpret_cast<f32x4*>(fbl + FR_BOUT * 1024) = bo4;
    } else {
        const int L = sec - 1;
#pragma unroll
        for (int t = 0; t < 4; ++t) {
            const int uo = slot16(t, m);
            const float* W = Whid + L * 4096 + uo;
#pragma unroll
            for (int kk = 0; kk < 2; ++kk) {
                unsigned w[4];
#pragma unroll
                for (int j2 = 0; j2 < 4; ++j2) {
                    int e0 = 32 * kk + 8 * qd + 2 * j2;
                    w[j2] = pkbf(INV2PI * W[e0 * 64], INV2PI * W[(e0 + 1) * 64]);
                }
                *reinterpret_cast<s16x8*>(fbl + FR_AH(L, t, kk) * 1024) = frag4(w[0], w[1], w[2], w[3]);
            }
            f32x4 bh;
#pragma unroll
            for (int i = 0; i < 4; ++i) bh[i] = INV2PI * bhid[L * 64 + slot16(t, 4 * qd + i)];
            *reinterpret_cast<f32x4*>(fbl + FR_BHD(L, t) * 1024) = bh;
        }
    }
}

__device__ __forceinline__ void trans16(const f32x4* C, s16x8& B0, s16x8& B1) {
    float a[4][4];
#pragma unroll
    for (int t = 0; t < 4; ++t)
#pragma unroll
        for (int i = 0; i < 4; ++i) a[t][i] = sinrev(C[t][i]);
    B0 = frag4(pkbf(a[0][0], a[0][1]), pkbf(a[0][2], a[0][3]),
               pkbf(a[1][0], a[1][1]), pkbf(a[1][2], a[1][3]));
    B1 = frag4(pkbf(a[2][0], a[2][1]), pkbf(a[2][2], a[2][3]),
               pkbf(a[3][0], a[3][1]), pkbf(a[3][2], a[3][3]));
}

__device__ __forceinline__ void trans16t(const f32x4* Cf, const f32x4* Ct,
                                         s16x8& Bf0, s16x8& Bf1,
                                         s16x8& Bt0, s16x8& Bt1)
{
    float s[4][4], d[4][4];
#pragma unroll
    for (int t = 0; t < 4; ++t)
#pragma unroll
        for (int i = 0; i < 4; ++i) {
            float cf = Cf[t][i];
            s[t][i] = sinrev(cf);
            d[t][i] = cosrev(cf) * (TWOPI_F * Ct[t][i]);
        }
    Bf0 = frag4(pkbf(s[0][0], s[0][1]), pkbf(s[0][2], s[0][3]),
                pkbf(s[1][0], s[1][1]), pkbf(s[1][2], s[1][3]));
    Bf1 = frag4(pkbf(s[2][0], s[2][1]), pkbf(s[2][2], s[2][3]),
                pkbf(s[3][0], s[3][1]), pkbf(s[3][2], s[3][3]));
    Bt0 = frag4(pkbf(d[0][0], d[0][1]), pkbf(d[0][2], d[0][3]),
                pkbf(d[1][0], d[1][1]), pkbf(d[1][2], d[1][3]));
    Bt1 = frag4(pkbf(d[2][0], d[2][1]), pkbf(d[2][2], d[2][3]),
                pkbf(d[3][0], d[3][1]), pkbf(d[3][2], d[3][3]));
}

__device__ __forceinline__ float grid_ylo(const float* __restrict__ y0p) {
    return floorf(y0p[0] * 8.0f) * 0.125f - 16.0f;
}

// forward-only eval (q-grid), frags from LDS at fbl = base + l*16
__device__ __forceinline__ float eval16_q(const char* fbl, const s16x8& Bty) {
    const f32x4 zc = {0.0f, 0.0f, 0.0f, 0.0f};
    f32x4 C[4];
#pragma unroll
    for (int t = 0; t < 4; ++t) {
        const s16x8 a  = *reinterpret_cast<const s16x8*>(fbl + FR_AIN(t) * 1024);
        const f32x4 bi = *reinterpret_cast<const f32x4*>(fbl + FR_BIN(t) * 1024);
        C[t] = __builtin_amdgcn_mfma_f32_16x16x32_bf16(a, Bty, bi, 0, 0, 0);
    }
    s16x8 B0, B1;
    trans16(C, B0, B1);
#pragma unroll
    for (int L = 0; L < 3; ++L) {
#pragma unroll
        for (int t = 0; t < 4; ++t) {
            const s16x8 a0 = *reinterpret_cast<const s16x8*>(fbl + FR_AH(L, t, 0) * 1024);
            const s16x8 a1 = *reinterpret_cast<const s16x8*>(fbl + FR_AH(L, t, 1) * 1024);
            const f32x4 bh = *reinterpret_cast<const f32x4*>(fbl + FR_BHD(L, t) * 1024);
            f32x4 c = __builtin_amdgcn_mfma_f32_16x16x32_bf16(a0, B0, bh, 0, 0, 0);
            C[t]    = __builtin_amdgcn_mfma_f32_16x16x32_bf16(a1, B1, c, 0, 0, 0);
        }
        trans16(C, B0, B1);
    }
    const s16x8 o0 = *reinterpret_cast<const s16x8*>(fbl + FR_AOUT(0) * 1024);
    const s16x8 o1 = *reinterpret_cast<const s16x8*>(fbl + FR_AOUT(1) * 1024);
    f32x4 Co = __builtin_amdgcn_mfma_f32_16x16x32_bf16(o0, B0, zc, 0, 0, 0);
    Co = __builtin_amdgcn_mfma_f32_16x16x32_bf16(o1, B1, Co, 0, 0, 0);
    return Co[0] + *reinterpret_cast<const float*>(fbl + FR_BOUT * 1024);
}

// fwd + tangent eval (Y-grid): returns Y and dY/dy at the 16 cols
__device__ __forceinline__ void eval16t(const char* fbl, const s16x8& Bty,
                                        const s16x8& Btn, float& Yv, float& dYv) {
    const f32x4 zc = {0.0f, 0.0f, 0.0f, 0.0f};
    f32x4 Cf[4], Ct[4];
#pragma unroll
    for (int t = 0; t < 4; ++t) {
        const s16x8 a  = *reinterpret_cast<const s16x8*>(fbl + FR_AIN(t) * 1024);
        const f32x4 bi = *reinterpret_cast<const f32x4*>(fbl + FR_BIN(t) * 1024);
        Cf[t] = __builtin_amdgcn_mfma_f32_16x16x32_bf16(a, Bty, bi, 0, 0, 0);
        Ct[t] = __builtin_amdgcn_mfma_f32_16x16x32_bf16(a, Btn, zc, 0, 0, 0);
    }
    s16x8 bf0, bf1, bt0, bt1;
    trans16t(Cf, Ct, bf0, bf1, bt0, bt1);
#pragma unroll
    for (int L = 0; L < 3; ++L) {
#pragma unroll
        for (int t = 0; t < 4; ++t) {
            const s16x8 a0 = *reinterpret_cast<const s16x8*>(fbl + FR_AH(L, t, 0) * 1024);
            const s16x8 a1 = *reinterpret_cast<const s16x8*>(fbl + FR_AH(L, t, 1) * 1024);
            const f32x4 bh = *reinterpret_cast<const f32x4*>(fbl + FR_BHD(L, t) * 1024);
            f32x4 c = __builtin_amdgcn_mfma_f32_16x16x32_bf16(a0, bf0, bh, 0, 0, 0);
            Cf[t]   = __builtin_amdgcn_mfma_f32_16x16x32_bf16(a1, bf1, c, 0, 0, 0);
            f32x4 z = __builtin_amdgcn_mfma_f32_16x16x32_bf16(a0, bt0, zc, 0, 0, 0);
            Ct[t]   = __builtin_amdgcn_mfma_f32_16x16x32_bf16(a1, bt1, z, 0, 0, 0);
        }
        trans16t(Cf, Ct, bf0, bf1, bt0, bt1);
    }
    const s16x8 o0 = *reinterpret_cast<const s16x8*>(fbl + FR_AOUT(0) * 1024);
    const s16x8 o1 = *reinterpret_cast<const s16x8*>(fbl + FR_AOUT(1) * 1024);
    f32x4 Cof = __builtin_amdgcn_mfma_f32_16x16x32_bf16(o0, bf0, zc, 0, 0, 0);
    Cof = __builtin_amdgcn_mfma_f32_16x16x32_bf16(o1, bf1, Cof, 0, 0, 0);
    f32x4 Cot = __builtin_amdgcn_mfma_f32_16x16x32_bf16(o0, bt0, zc, 0, 0, 0);
    Cot = __builtin_amdgcn_mfma_f32_16x16x32_bf16(o1, bt1, Cot, 0, 0, 0);
    Yv  = Cof[0] + *reinterpret_cast<const float*>(fbl + FR_BOUT * 1024);
    dYv = Cot[0];
}

// Catmull-Rom (identical formula to r16-r20's q interp)
__device__ __forceinline__ float cmr(const float* row, float fr) {
    const float q0 = row[-1], q1 = row[0], q2 = row[1], q3 = row[2];
    return q1 + 0.5f * fr * ((q2 - q0)
             + fr * ((2.0f * q0 - 5.0f * q1 + 4.0f * q2 - q3)
             + fr * (3.0f * (q1 - q2) + q3 - q0)));
}

// ====================== the single fused kernel ======================

extern "C" __global__ void __launch_bounds__(1024, 4)
fbsnn_one(const float* __restrict__ Y_Win, const float* __restrict__ Y_bin,
          const float* __restrict__ Y_Whid, const float* __restrict__ Y_bhid,
          const float* __restrict__ Y_Wout, const float* __restrict__ Y_bout,
          const float* __restrict__ q_Win, const float* __restrict__ q_bin,
          const float* __restrict__ q_Whid, const float* __restrict__ q_bhid,
          const float* __restrict__ q_Wout, const float* __restrict__ q_bout,
          const float* __restrict__ y0p, const float* __restrict__ dW,
          float* __restrict__ ws, float* __restrict__ out)
{
    extern __shared__ __align__(16) float sf[];
    float* qg  = sf + L_QG;
    float* Yg  = sf + L_YG;
    float* dYg = sf + L_DYG;
    float* dWb = sf + L_DW;

    int* done = (int*)ws;
    unsigned long long* pairs = (unsigned long long*)(ws + WS_PAIR);

    const int tid = (int)threadIdx.x;
    const int wv  = tid >> 6;
    const int l   = tid & 63;
    const int qd  = l >> 4;            // grid-eval lane decomposition
    const int mm  = l & 15;
    const int blk = (int)blockIdx.x;

    const bool is_q = (blk < NSTEP);                       // rows 0..49
    const bool is_y = (blk >= 64 && blk < 64 + NSTEP + 1); // rows 0..50

    const float ylo = grid_ylo(y0p);

    // ---- phase A: frag build (waves 0-3) + dW slab staging (waves 8-15) ----
    if (wv < 4) {
        if (is_q)
            build_sec(wv, q_Win, q_bin, q_Whid, q_bhid, q_Wout, q_bout, qd, mm,
                      (char*)(sf + L_QG) + l * 16);
        else if (is_y)
            build_sec(wv, Y_Win, Y_bin, Y_Whid, Y_bhid, Y_Wout, Y_bout, qd, mm,
                      (char*)(sf + L_YG) + l * 16);
    } else if (wv >= 8) {
        // 512 threads stage 50x32 dW floats (128 B per row, coalesced)
        for (int idx = tid - 512; idx < NSTEP * PPB; idx += 512)
            dWb[idx] = dW[(idx >> 5) * NPATH + blk * PPB + (idx & (PPB - 1))];
    }
    __syncthreads();                                       // B1

    // ---- phase A: grid tabulation (one row per grid block, 16 waves) ----
    if (is_q) {
        const char* fbl = (const char*)(sf + L_QG) + l * 16;
        const float tt = blk * DT_F;
        const float yg = ylo + (float)(16 * wv + mm) * GRID_DY;  // k/8 exact bf16
        const s16x8 Bty = frag4((qd == 0) ? pkbf(tt, yg) : 0u, 0u, 0u, 0u);
        const float qv = eval16_q(fbl, Bty);
        if (qd == 0) ws[WS_QG + blk * GRID_N + 16 * wv + mm] = qv;
    } else if (is_y) {
        const char* fbl = (const char*)(sf + L_YG) + l * 16;
        const int   n   = blk - 64;
        const float tt  = n * DT_F;
        const float yg  = ylo + (float)(16 * wv + mm) * GRID_DY;
        const s16x8 Bty = frag4((qd == 0) ? pkbf(tt, yg) : 0u, 0u, 0u, 0u);
        const s16x8 Btn = frag4((qd == 0) ? pkbf(0.0f, 1.0f) : 0u, 0u, 0u, 0u);
        float Yv, dYv;
        eval16t(fbl, Bty, Btn, Yv, dYv);
        if (qd == 0) {
            ws[WS_YG  + n * GRID_N + 16 * wv + mm] = Yv;
            ws[WS_DYG + n * GRID_N + 16 * wv + mm] = dYv;
        }
    }
    __syncthreads();                                       // B2

    if ((is_q || is_y) && tid == 0) {
        __threadfence();   // release: L2 writeback of this block's rows
        __hip_atomic_store(&done[blk], (int)MAGIC, __ATOMIC_RELAXED,
                           __HIP_MEMORY_SCOPE_AGENT);
    }

    // ---- device barrier: wave 0 spins on the 101 sentinels ----
    if (wv == 0) {
        if (l < NSTEP)          // q rows: slots 0..49
            while (__hip_atomic_load(&done[l], __ATOMIC_RELAXED,
                                     __HIP_MEMORY_SCOPE_AGENT) != (int)MAGIC)
                __builtin_amdgcn_s_sleep(8);
        if (l < NSTEP + 1)      // Y rows: slots 64..114
            while (__hip_atomic_load(&done[64 + l], __ATOMIC_RELAXED,
                                     __HIP_MEMORY_SCOPE_AGENT) != (int)MAGIC)
                __builtin_amdgcn_s_sleep(8);
        __threadfence();        // acquire: invalidate before staging reads
    }
    __syncthreads();                                       // B3

    // ---- stage: all 3 grids ws -> LDS (9728 x 16B, coalesced) ----
#pragma unroll
    for (int k = 0; k < 10; ++k) {
        const int idx = tid + k * 1024;
        if (idx < ((L_DW) / 4))
            ((float4v*)sf)[idx] = ((const float4v*)(ws + WS_QG))[idx];
    }
    __syncthreads();                                       // B4

    if (wv != 0) return;       // waves 1-15 done (no further barriers)

    // ---- phase B: scan + interp + inline residuals (wave 0 only) ----
    // LDS-only loop: zero global memory operations.
    const int m = l & (PPB - 1);           // path within block (lanes 32-63 dup)

    float y   = y0p[0];
    float acc = 0.0f;
    float Yp = 0.0f, dYp = 0.0f, qp = 0.0f, dwp = 0.0f;

    for (int n = 0; n < NSTEP; ++n) {
        const float dwv = dWb[n * PPB + m];

        float u = (y - ylo) * GRID_INV;
        u = fminf(fmaxf(u, 1.0f), 253.999f);
        int i = (int)u;
        if (i > 253) i = 253;
        const float fr = u - (float)i;

        const float qn  = cmr(qg  + n * GRID_N + i, fr);
        const float Yn  = cmr(Yg  + n * GRID_N + i, fr);
        const float dYn = cmr(dYg + n * GRID_N + i, fr);

        if (n) {   // residual for step n-1: Y_n vs Y_tilde(n-1)
            const float r = Yn - (fmaf(-qp * qp, DT_F, Yp)
                                  + (SIGMA_F * dYp) * (dwp * SQRT_DT));
            acc = fmaf(r, r, acc);
        }
        qp = qn; Yp = Yn; dYp = dYn; dwp = dwv;
        y = fmaf(qn, DT_F, y) + SIGMA_F * (dwv * SQRT_DT);
    }
    {   // terminal row 50: last residual + terminal costs
        float u = (y - ylo) * GRID_INV;
        u = fminf(fmaxf(u, 1.0f), 253.999f);
        int i = (int)u;
        if (i > 253) i = 253;
        const float fr = u - (float)i;
        const float Y50  = cmr(Yg  + NSTEP * GRID_N + i, fr);
        const float dY50 = cmr(dYg + NSTEP * GRID_N + i, fr);
        const float r = Y50 - (fmaf(-qp * qp, DT_F, Yp)
                               + (SIGMA_F * dYp) * (dwp * SQRT_DT));
        acc = fmaf(r, r, acc);
        const float r1 = Y50 - y * y;
        const float r2 = dY50 - 2.0f * y;
        acc = fmaf(r1, r1, fmaf(r2, r2, acc));
    }
    if (l >= PPB) acc = 0.0f;              // drop duplicated lanes

#pragma unroll
    for (int off = 32; off > 0; off >>= 1) acc += __shfl_down(acc, off, 64);

    // ---- cross-block reduction via {MAGIC,float} sentinel pairs ----
    if (l == 0) {
        const unsigned long long pv =
            ((unsigned long long)MAGIC << 32) |
            (unsigned long long)__float_as_uint(acc);
        __hip_atomic_store(&pairs[blk], pv, __ATOMIC_RELAXED,
                           __HIP_MEMORY_SCOPE_AGENT);
    }
    if (blk == 0) {
        float s = 0.0f;
#pragma unroll
        for (int r = 0; r < 2; ++r) {
            unsigned long long v;
            while ((unsigned)((v = __hip_atomic_load(&pairs[64 * r + l],
                            __ATOMIC_RELAXED, __HIP_MEMORY_SCOPE_AGENT)) >> 32)
                   != MAGIC)
                __builtin_amdgcn_s_sleep(4);
            s += __uint_as_float((unsigned)(v & 0xffffffffu));
        }
#pragma unroll
        for (int off = 32; off > 0; off >>= 1) s += __shfl_down(s, off, 64);
        if (l == 0) out[0] = s * (1.0f / (float)NPATH);
    }
}

// ================= host launch =================

extern "C" void kernel_launch(void* const* d_in, const int* in_sizes, int n_in,
                              void* d_out, int out_size, void* d_ws, size_t ws_size,
                              hipStream_t stream)
{
    const float* Y_Win  = (const float*)d_in[0];
    const float* Y_bin  = (const float*)d_in[1];
    const float* Y_Whid = (const float*)d_in[2];
    const float* Y_bhid = (const float*)d_in[3];
    const float* Y_Wout = (const float*)d_in[4];
    const float* Y_bout = (const float*)d_in[5];
    const float* q_Win  = (const float*)d_in[6];
    const float* q_bin  = (const float*)d_in[7];
    const float* q_Whid = (const float*)d_in[8];
    const float* q_bhid = (const float*)d_in[9];
    const float* q_Wout = (const float*)d_in[10];
    const float* q_bout = (const float*)d_in[11];
    const float* y0p    = (const float*)d_in[12];
    const float* dW     = (const float*)d_in[13];

    fbsnn_one<<<dim3(NBLK), dim3(1024), SMEM_BYTES, stream>>>(
        Y_Win, Y_bin, Y_Whid, Y_bhid, Y_Wout, Y_bout,
        q_Win, q_bin, q_Whid, q_bhid, q_Wout, q_bout,
        y0p, dW, (float*)d_ws, (float*)d_out);
}

// Round 7
// 100.104 us; speedup vs baseline: 1.2133x; 1.0449x over previous
//
#include <hip/hip_runtime.h>

// FBSNN loss — single dispatch, everything tabulated on the y-grid.
//
// Round 22 = round 21 with the grid/blocks rightsized:
//   * GRID_N 256 -> 128 (range [y0-8, y0+8), same 1/8 spacing; path
//     excursion <= ~4.5, nodes are the SAME absolute y values -> in-range
//     interp bitwise identical). Halves grid evals, staging, LDS.
//   * 2 rows per producer block -> 51 producers (0..24 q, 32..57 Y);
//     frag-build area aliases the Y/dY grid LDS (phase-A only).
//   * 64 blocks x 64 paths (full wave, no duplicated lanes): stage traffic
//     halves again (64 x 76 KB = 4.9 MB), 64-entry pair gather.
//   * s_sleep(2) spin polls (~128 cyc) at both rendezvous.
// Structure otherwise identical to r21:
//   Phase A: producers build frags -> LDS, tabulate grid rows, store to ws,
//            release fence, MAGIC sentinel (poison/replay-proof).
//            Waves 8-15 of every block stage the dW slab -> LDS.
//   Barrier: wave 0 spins on 51 sentinels, acquire fence, syncthreads.
//   Stage:   3 grids (19456 floats, contiguous) ws -> LDS, coalesced.
//   Phase B: waves 1-15 exit. Wave 0: 50-step scan for 64 paths, q/Y/dY
//            Catmull-Rom interp + inline residuals — pure LDS+VALU loop.
//   Reduce:  per-block {MAGIC,float} pair; block 0 gathers 64 pairs.

#define NPATH   4096
#define NSTEP   50
#define DT_F    0.02f
#define SQRT_DT 0.14142136f
#define SIGMA_F 0.5f
#define INV2PI  0.15915494309189535f
#define TWOPI_F 6.28318530717958648f

#define GRID_N   128
#define GRID_INV 8.0f
#define GRID_DY  0.125f

#define NBLK    64
#define PPB     64                          // paths per block (one full wave)

#define QG_FLOATS  (NSTEP * GRID_N)         // 6400
#define YG_FLOATS  ((NSTEP + 1) * GRID_N)   // 6528

#define MAGIC 0x5AB1C0DEu

// fragment ids (16B per lane each)
#define FR_AIN(t)     (t)
#define FR_AH(L,t,kk) (4 + (L)*8 + (t)*2 + (kk))
#define FR_AOUT(kk)   (28 + (kk))
#define FR_BIN(t)     (30 + (t))
#define FR_BHD(L,t)   (34 + (L)*4 + (t))
#define FR_BOUT       46
#define FRAG_FLOATS   (47 * 64 * 4)         // 12032

// workspace layout (float offsets)
#define WS_DONE 0                           // 64 ints (sentinel per block id)
#define WS_QG   64                          // 6400
#define WS_YG   (WS_QG + QG_FLOATS)         // 6464
#define WS_DYG  (WS_YG + YG_FLOATS)         // 12992
#define WS_PAIR (WS_DYG + YG_FLOATS)        // 19520: 64 x {MAGIC,float} u64

// LDS layout (float offsets) — grids contiguous for one-shot staging.
// Frag-build area aliases L_YG.. (phase A only; grids staged after B3).
#define L_QG    0                           // 6400
#define L_YG    QG_FLOATS                   // 6400  (+6528)
#define L_DYG   (L_YG + YG_FLOATS)          // 12928 (+6528)
#define L_FB    L_YG                        // build area: 12032 fl < 13056 ✓
#define L_DW    (L_DYG + YG_FLOATS)         // 19456  (50*64 dW slab)
#define SMEM_FLOATS (L_DW + NSTEP * PPB)    // 22656
#define SMEM_BYTES  (SMEM_FLOATS * 4)       // 90,624 B

typedef __attribute__((ext_vector_type(8)))  short s16x8;
typedef __attribute__((ext_vector_type(4)))  float f32x4;
typedef __attribute__((ext_vector_type(4)))  float float4v;

#if __has_builtin(__builtin_amdgcn_cvt_pk_bf16_f32)
__device__ __forceinline__ unsigned pkbf(float a, float b) {
    auto r = __builtin_amdgcn_cvt_pk_bf16_f32(a, b);
    unsigned u; __builtin_memcpy(&u, &r, 4); return u;
}
#else
__device__ __forceinline__ unsigned pkbf(float a, float b) {
    unsigned ua = __float_as_uint(a), ub = __float_as_uint(b);
    ua += 0x7fffu + ((ua >> 16) & 1u);
    ub += 0x7fffu + ((ub >> 16) & 1u);
    return (ua >> 16) | (ub & 0xffff0000u);
}
#endif

__device__ __forceinline__ s16x8 frag4(unsigned a, unsigned b, unsigned c, unsigned d) {
    union { unsigned u[4]; s16x8 s; } x;
    x.u[0] = a; x.u[1] = b; x.u[2] = c; x.u[3] = d;
    return x.s;
}

__device__ __forceinline__ float sinrev(float x) {
#if __has_builtin(__builtin_amdgcn_sinf)
    return __builtin_amdgcn_sinf(x);
#else
    return __sinf(x * TWOPI_F);
#endif
}
__device__ __forceinline__ float cosrev(float x) {
#if __has_builtin(__builtin_amdgcn_cosf)
    return __builtin_amdgcn_cosf(x);
#else
    return __cosf(x * TWOPI_F);
#endif
}

__device__ __forceinline__ int slot16(int t, int r) {
    return (t < 2) ? 8 * (r >> 2) + 4 * t + (r & 3)
                   : 32 + 8 * (r >> 2) + 4 * (t - 2) + (r & 3);
}

// Build one section of a net's fragments straight into LDS.
__device__ __forceinline__ void build_sec(
    int sec, const float* __restrict__ Win, const float* __restrict__ bin,
    const float* __restrict__ Whid, const float* __restrict__ bhid,
    const float* __restrict__ Wout, const float* __restrict__ bo,
    int qd, int m, char* fbl)
{
    if (sec == 0) {
#pragma unroll
        for (int t = 0; t < 4; ++t) {
            const int uo = slot16(t, m);
            unsigned w0 = 0;
            if (qd == 0) w0 = pkbf(INV2PI * Win[uo], INV2PI * Win[64 + uo]);
            *reinterpret_cast<s16x8*>(fbl + FR_AIN(t) * 1024) = frag4(w0, 0u, 0u, 0u);
            f32x4 bi;
#pragma unroll
            for (int i = 0; i < 4; ++i) bi[i] = INV2PI * bin[slot16(t, 4 * qd + i)];
            *reinterpret_cast<f32x4*>(fbl + FR_BIN(t) * 1024) = bi;
        }
#pragma unroll
        for (int kk = 0; kk < 2; ++kk) {
            unsigned w[4] = {0u, 0u, 0u, 0u};
            if (m == 0) {
#pragma unroll
                for (int j2 = 0; j2 < 4; ++j2) {
                    int e0 = 32 * kk + 8 * qd + 2 * j2;
                    w[j2] = pkbf(Wout[e0], Wout[e0 + 1]);
                }
            }
            *reinterpret_cast<s16x8*>(fbl + FR_AOUT(kk) * 1024) = frag4(w[0], w[1], w[2], w[3]);
        }
        f32x4 bo4 = {bo[0], 0.0f, 0.0f, 0.0f};
        *reinterpret_cast<f32x4*>(fbl + FR_BOUT * 1024) = bo4;
    } else {
        const int L = sec - 1;
#pragma unroll
        for (int t = 0; t < 4; ++t) {
            const int uo = slot16(t, m);
            const float* W = Whid + L * 4096 + uo;
#pragma unroll
            for (int kk = 0; kk < 2; ++kk) {
                unsigned w[4];
#pragma unroll
                for (int j2 = 0; j2 < 4; ++j2) {
                    int e0 = 32 * kk + 8 * qd + 2 * j2;
                    w[j2] = pkbf(INV2PI * W[e0 * 64], INV2PI * W[(e0 + 1) * 64]);
                }
                *reinterpret_cast<s16x8*>(fbl + FR_AH(L, t, kk) * 1024) = frag4(w[0], w[1], w[2], w[3]);
            }
            f32x4 bh;
#pragma unroll
            for (int i = 0; i < 4; ++i) bh[i] = INV2PI * bhid[L * 64 + slot16(t, 4 * qd + i)];
            *reinterpret_cast<f32x4*>(fbl + FR_BHD(L, t) * 1024) = bh;
        }
    }
}

__device__ __forceinline__ void trans16(const f32x4* C, s16x8& B0, s16x8& B1) {
    float a[4][4];
#pragma unroll
    for (int t = 0; t < 4; ++t)
#pragma unroll
        for (int i = 0; i < 4; ++i) a[t][i] = sinrev(C[t][i]);
    B0 = frag4(pkbf(a[0][0], a[0][1]), pkbf(a[0][2], a[0][3]),
               pkbf(a[1][0], a[1][1]), pkbf(a[1][2], a[1][3]));
    B1 = frag4(pkbf(a[2][0], a[2][1]), pkbf(a[2][2], a[2][3]),
               pkbf(a[3][0], a[3][1]), pkbf(a[3][2], a[3][3]));
}

__device__ __forceinline__ void trans16t(const f32x4* Cf, const f32x4* Ct,
                                         s16x8& Bf0, s16x8& Bf1,
                                         s16x8& Bt0, s16x8& Bt1)
{
    float s[4][4], d[4][4];
#pragma unroll
    for (int t = 0; t < 4; ++t)
#pragma unroll
        for (int i = 0; i < 4; ++i) {
            float cf = Cf[t][i];
            s[t][i] = sinrev(cf);
            d[t][i] = cosrev(cf) * (TWOPI_F * Ct[t][i]);
        }
    Bf0 = frag4(pkbf(s[0][0], s[0][1]), pkbf(s[0][2], s[0][3]),
                pkbf(s[1][0], s[1][1]), pkbf(s[1][2], s[1][3]));
    Bf1 = frag4(pkbf(s[2][0], s[2][1]), pkbf(s[2][2], s[2][3]),
                pkbf(s[3][0], s[3][1]), pkbf(s[3][2], s[3][3]));
    Bt0 = frag4(pkbf(d[0][0], d[0][1]), pkbf(d[0][2], d[0][3]),
                pkbf(d[1][0], d[1][1]), pkbf(d[1][2], d[1][3]));
    Bt1 = frag4(pkbf(d[2][0], d[2][1]), pkbf(d[2][2], d[2][3]),
                pkbf(d[3][0], d[3][1]), pkbf(d[3][2], d[3][3]));
}

__device__ __forceinline__ float grid_ylo(const float* __restrict__ y0p) {
    return floorf(y0p[0] * 8.0f) * 0.125f - 8.0f;
}

// forward-only eval (q-grid), frags from LDS at fbl = base + l*16
__device__ __forceinline__ float eval16_q(const char* fbl, const s16x8& Bty) {
    const f32x4 zc = {0.0f, 0.0f, 0.0f, 0.0f};
    f32x4 C[4];
#pragma unroll
    for (int t = 0; t < 4; ++t) {
        const s16x8 a  = *reinterpret_cast<const s16x8*>(fbl + FR_AIN(t) * 1024);
        const f32x4 bi = *reinterpret_cast<const f32x4*>(fbl + FR_BIN(t) * 1024);
        C[t] = __builtin_amdgcn_mfma_f32_16x16x32_bf16(a, Bty, bi, 0, 0, 0);
    }
    s16x8 B0, B1;
    trans16(C, B0, B1);
#pragma unroll
    for (int L = 0; L < 3; ++L) {
#pragma unroll
        for (int t = 0; t < 4; ++t) {
            const s16x8 a0 = *reinterpret_cast<const s16x8*>(fbl + FR_AH(L, t, 0) * 1024);
            const s16x8 a1 = *reinterpret_cast<const s16x8*>(fbl + FR_AH(L, t, 1) * 1024);
            const f32x4 bh = *reinterpret_cast<const f32x4*>(fbl + FR_BHD(L, t) * 1024);
            f32x4 c = __builtin_amdgcn_mfma_f32_16x16x32_bf16(a0, B0, bh, 0, 0, 0);
            C[t]    = __builtin_amdgcn_mfma_f32_16x16x32_bf16(a1, B1, c, 0, 0, 0);
        }
        trans16(C, B0, B1);
    }
    const s16x8 o0 = *reinterpret_cast<const s16x8*>(fbl + FR_AOUT(0) * 1024);
    const s16x8 o1 = *reinterpret_cast<const s16x8*>(fbl + FR_AOUT(1) * 1024);
    f32x4 Co = __builtin_amdgcn_mfma_f32_16x16x32_bf16(o0, B0, zc, 0, 0, 0);
    Co = __builtin_amdgcn_mfma_f32_16x16x32_bf16(o1, B1, Co, 0, 0, 0);
    return Co[0] + *reinterpret_cast<const float*>(fbl + FR_BOUT * 1024);
}

// fwd + tangent eval (Y-grid): returns Y and dY/dy at the 16 cols
__device__ __forceinline__ void eval16t(const char* fbl, const s16x8& Bty,
                                        const s16x8& Btn, float& Yv, float& dYv) {
    const f32x4 zc = {0.0f, 0.0f, 0.0f, 0.0f};
    f32x4 Cf[4], Ct[4];
#pragma unroll
    for (int t = 0; t < 4; ++t) {
        const s16x8 a  = *reinterpret_cast<const s16x8*>(fbl + FR_AIN(t) * 1024);
        const f32x4 bi = *reinterpret_cast<const f32x4*>(fbl + FR_BIN(t) * 1024);
        Cf[t] = __builtin_amdgcn_mfma_f32_16x16x32_bf16(a, Bty, bi, 0, 0, 0);
        Ct[t] = __builtin_amdgcn_mfma_f32_16x16x32_bf16(a, Btn, zc, 0, 0, 0);
    }
    s16x8 bf0, bf1, bt0, bt1;
    trans16t(Cf, Ct, bf0, bf1, bt0, bt1);
#pragma unroll
    for (int L = 0; L < 3; ++L) {
#pragma unroll
        for (int t = 0; t < 4; ++t) {
            const s16x8 a0 = *reinterpret_cast<const s16x8*>(fbl + FR_AH(L, t, 0) * 1024);
            const s16x8 a1 = *reinterpret_cast<const s16x8*>(fbl + FR_AH(L, t, 1) * 1024);
            const f32x4 bh = *reinterpret_cast<const f32x4*>(fbl + FR_BHD(L, t) * 1024);
            f32x4 c = __builtin_amdgcn_mfma_f32_16x16x32_bf16(a0, bf0, bh, 0, 0, 0);
            Cf[t]   = __builtin_amdgcn_mfma_f32_16x16x32_bf16(a1, bf1, c, 0, 0, 0);
            f32x4 z = __builtin_amdgcn_mfma_f32_16x16x32_bf16(a0, bt0, zc, 0, 0, 0);
            Ct[t]   = __builtin_amdgcn_mfma_f32_16x16x32_bf16(a1, bt1, z, 0, 0, 0);
        }
        trans16t(Cf, Ct, bf0, bf1, bt0, bt1);
    }
    const s16x8 o0 = *reinterpret_cast<const s16x8*>(fbl + FR_AOUT(0) * 1024);
    const s16x8 o1 = *reinterpret_cast<const s16x8*>(fbl + FR_AOUT(1) * 1024);
    f32x4 Cof = __builtin_amdgcn_mfma_f32_16x16x32_bf16(o0, bf0, zc, 0, 0, 0);
    Cof = __builtin_amdgcn_mfma_f32_16x16x32_bf16(o1, bf1, Cof, 0, 0, 0);
    f32x4 Cot = __builtin_amdgcn_mfma_f32_16x16x32_bf16(o0, bt0, zc, 0, 0, 0);
    Cot = __builtin_amdgcn_mfma_f32_16x16x32_bf16(o1, bt1, Cot, 0, 0, 0);
    Yv  = Cof[0] + *reinterpret_cast<const float*>(fbl + FR_BOUT * 1024);
    dYv = Cot[0];
}

// Catmull-Rom (identical formula to r16-r21)
__device__ __forceinline__ float cmr(const float* row, float fr) {
    const float q0 = row[-1], q1 = row[0], q2 = row[1], q3 = row[2];
    return q1 + 0.5f * fr * ((q2 - q0)
             + fr * ((2.0f * q0 - 5.0f * q1 + 4.0f * q2 - q3)
             + fr * (3.0f * (q1 - q2) + q3 - q0)));
}

// ====================== the single fused kernel ======================

extern "C" __global__ void __launch_bounds__(1024, 4)
fbsnn_one(const float* __restrict__ Y_Win, const float* __restrict__ Y_bin,
          const float* __restrict__ Y_Whid, const float* __restrict__ Y_bhid,
          const float* __restrict__ Y_Wout, const float* __restrict__ Y_bout,
          const float* __restrict__ q_Win, const float* __restrict__ q_bin,
          const float* __restrict__ q_Whid, const float* __restrict__ q_bhid,
          const float* __restrict__ q_Wout, const float* __restrict__ q_bout,
          const float* __restrict__ y0p, const float* __restrict__ dW,
          float* __restrict__ ws, float* __restrict__ out)
{
    extern __shared__ __align__(16) float sf[];
    float* qg  = sf + L_QG;
    float* Yg  = sf + L_YG;
    float* dYg = sf + L_DYG;
    float* dWb = sf + L_DW;

    int* done = (int*)ws;
    unsigned long long* pairs = (unsigned long long*)(ws + WS_PAIR);

    const int tid = (int)threadIdx.x;
    const int wv  = tid >> 6;
    const int l   = tid & 63;
    const int qd  = l >> 4;            // grid-eval lane decomposition
    const int mm  = l & 15;
    const int blk = (int)blockIdx.x;

    const bool is_q = (blk < 25);                    // q rows 2b, 2b+1
    const bool is_y = (blk >= 32 && blk < 58);       // Y rows 2(b-32), +1

    const float ylo = grid_ylo(y0p);

    // ---- phase A: frag build (waves 0-3) + dW slab staging (waves 8-15) ----
    if (wv < 4) {
        char* fbl = (char*)(sf + L_FB) + l * 16;
        if (is_q)
            build_sec(wv, q_Win, q_bin, q_Whid, q_bhid, q_Wout, q_bout, qd, mm, fbl);
        else if (is_y)
            build_sec(wv, Y_Win, Y_bin, Y_Whid, Y_bhid, Y_Wout, Y_bout, qd, mm, fbl);
    } else if (wv >= 8) {
        // 512 threads stage 50x64 dW floats (256 B per row, coalesced)
        for (int idx = tid - 512; idx < NSTEP * PPB; idx += 512)
            dWb[idx] = dW[(idx >> 6) * NPATH + blk * PPB + (idx & (PPB - 1))];
    }
    __syncthreads();                                       // B1

    // ---- phase A: grid tabulation (2 rows per producer, 8 waves/row) ----
    if (is_q || is_y) {
        const char* fbl = (const char*)(sf + L_FB) + l * 16;
        const int rib  = wv >> 3;                          // row in block
        const int colg = wv & 7;
        const int col  = 16 * colg + mm;
        const int n    = is_q ? (2 * blk + rib) : (2 * (blk - 32) + rib);
        const bool valid = is_q ? (n < NSTEP) : (n <= NSTEP);
        if (valid) {
            const float tt = n * DT_F;
            const float yg = ylo + (float)col * GRID_DY;   // k/8: exact bf16
            const s16x8 Bty = frag4((qd == 0) ? pkbf(tt, yg) : 0u, 0u, 0u, 0u);
            if (is_q) {
                const float qv = eval16_q(fbl, Bty);
                if (qd == 0) ws[WS_QG + n * GRID_N + col] = qv;
            } else {
                const s16x8 Btn = frag4((qd == 0) ? pkbf(0.0f, 1.0f) : 0u, 0u, 0u, 0u);
                float Yv, dYv;
                eval16t(fbl, Bty, Btn, Yv, dYv);
                if (qd == 0) {
                    ws[WS_YG  + n * GRID_N + col] = Yv;
                    ws[WS_DYG + n * GRID_N + col] = dYv;
                }
            }
        }
    }
    __syncthreads();                                       // B2

    if ((is_q || is_y) && tid == 0) {
        __threadfence();   // release: writeback of this block's rows
        __hip_atomic_store(&done[blk], (int)MAGIC, __ATOMIC_RELAXED,
                           __HIP_MEMORY_SCOPE_AGENT);
    }

    // ---- device barrier: wave 0 spins on the 51 sentinels ----
    if (wv == 0) {
        if (l < 25)             // q producers: blocks 0..24
            while (__hip_atomic_load(&done[l], __ATOMIC_RELAXED,
                                     __HIP_MEMORY_SCOPE_AGENT) != (int)MAGIC)
                __builtin_amdgcn_s_sleep(2);
        if (l < 26)             // Y producers: blocks 32..57
            while (__hip_atomic_load(&done[32 + l], __ATOMIC_RELAXED,
                                     __HIP_MEMORY_SCOPE_AGENT) != (int)MAGIC)
                __builtin_amdgcn_s_sleep(2);
        __threadfence();        // acquire: invalidate before staging reads
    }
    __syncthreads();                                       // B3

    // ---- stage: all 3 grids ws -> LDS (4864 x 16B, coalesced) ----
#pragma unroll
    for (int k = 0; k < 5; ++k) {
        const int idx = tid + k * 1024;
        if (idx < (L_DW / 4))
            ((float4v*)sf)[idx] = ((const float4v*)(ws + WS_QG))[idx];
    }
    __syncthreads();                                       // B4

    if (wv != 0) return;       // waves 1-15 done (no further barriers)

    // ---- phase B: scan + interp + inline residuals (wave 0, 64 paths) ----
    // LDS-only loop: zero global memory operations.
    float y   = y0p[0];
    float acc = 0.0f;
    float Yp = 0.0f, dYp = 0.0f, qp = 0.0f, dwp = 0.0f;

    for (int n = 0; n < NSTEP; ++n) {
        const float dwv = dWb[n * PPB + l];

        float u = (y - ylo) * GRID_INV;
        u = fminf(fmaxf(u, 1.0f), 125.999f);
        int i = (int)u;
        if (i > 125) i = 125;
        const float fr = u - (float)i;

        const float qn  = cmr(qg  + n * GRID_N + i, fr);
        const float Yn  = cmr(Yg  + n * GRID_N + i, fr);
        const float dYn = cmr(dYg + n * GRID_N + i, fr);

        if (n) {   // residual for step n-1: Y_n vs Y_tilde(n-1)
            const float r = Yn - (fmaf(-qp * qp, DT_F, Yp)
                                  + (SIGMA_F * dYp) * (dwp * SQRT_DT));
            acc = fmaf(r, r, acc);
        }
        qp = qn; Yp = Yn; dYp = dYn; dwp = dwv;
        y = fmaf(qn, DT_F, y) + SIGMA_F * (dwv * SQRT_DT);
    }
    {   // terminal row 50: last residual + terminal costs
        float u = (y - ylo) * GRID_INV;
        u = fminf(fmaxf(u, 1.0f), 125.999f);
        int i = (int)u;
        if (i > 125) i = 125;
        const float fr = u - (float)i;
        const float Y50  = cmr(Yg  + NSTEP * GRID_N + i, fr);
        const float dY50 = cmr(dYg + NSTEP * GRID_N + i, fr);
        const float r = Y50 - (fmaf(-qp * qp, DT_F, Yp)
                               + (SIGMA_F * dYp) * (dwp * SQRT_DT));
        acc = fmaf(r, r, acc);
        const float r1 = Y50 - y * y;
        const float r2 = dY50 - 2.0f * y;
        acc = fmaf(r1, r1, fmaf(r2, r2, acc));
    }

#pragma unroll
    for (int off = 32; off > 0; off >>= 1) acc += __shfl_down(acc, off, 64);

    // ---- cross-block reduction via {MAGIC,float} sentinel pairs ----
    if (l == 0) {
        const unsigned long long pv =
            ((unsigned long long)MAGIC << 32) |
            (unsigned long long)__float_as_uint(acc);
        __hip_atomic_store(&pairs[blk], pv, __ATOMIC_RELAXED,
                           __HIP_MEMORY_SCOPE_AGENT);
    }
    if (blk == 0) {
        unsigned long long v;
        while ((unsigned)((v = __hip_atomic_load(&pairs[l], __ATOMIC_RELAXED,
                        __HIP_MEMORY_SCOPE_AGENT)) >> 32) != MAGIC)
            __builtin_amdgcn_s_sleep(2);
        float s = __uint_as_float((unsigned)(v & 0xffffffffu));
#pragma unroll
        for (int off = 32; off > 0; off >>= 1) s += __shfl_down(s, off, 64);
        if (l == 0) out[0] = s * (1.0f / (float)NPATH);
    }
}

// ================= host launch =================

extern "C" void kernel_launch(void* const* d_in, const int* in_sizes, int n_in,
                              void* d_out, int out_size, void* d_ws, size_t ws_size,
                              hipStream_t stream)
{
    const float* Y_Win  = (const float*)d_in[0];
    const float* Y_bin  = (const float*)d_in[1];
    const float* Y_Whid = (const float*)d_in[2];
    const float* Y_bhid = (const float*)d_in[3];
    const float* Y_Wout = (const float*)d_in[4];
    const float* Y_bout = (const float*)d_in[5];
    const float* q_Win  = (const float*)d_in[6];
    const float* q_bin  = (const float*)d_in[7];
    const float* q_Whid = (const float*)d_in[8];
    const float* q_bhid = (const float*)d_in[9];
    const float* q_Wout = (const float*)d_in[10];
    const float* q_bout = (const float*)d_in[11];
    const float* y0p    = (const float*)d_in[12];
    const float* dW     = (const float*)d_in[13];

    fbsnn_one<<<dim3(NBLK), dim3(1024), SMEM_BYTES, stream>>>(
        Y_Win, Y_bin, Y_Whid, Y_bhid, Y_Wout, Y_bout,
        q_Win, q_bin, q_Whid, q_bhid, q_Wout, q_bout,
        y0p, dW, (float*)d_ws, (float*)d_out);
}